// Round 6
// baseline (330.154 us; speedup 1.0000x reference)
//
#include <hip/hip_runtime.h>
#include <hip/hip_bf16.h>

// B=8, T=512, N=64, E=128, H=256, P=96.  bn = b*64+n (512 rows).
// Identities:
//  xe = x_noD*emb  => rfft factorizes: spectral scalar s[bn,k] (packed: k<=256 real, k>256 imag)
//  mlp(s*emb) piecewise-linear in s (257 regions; tables Atab/Btab[r][e])
//  xt-part of flat@fw1:  h2[bn,h] = sum_{k,e} Yp[bn,k,e] * M2[k,e,h],
//      M2[k,(h,e)] = sum_t W[t,k] fw1[(t*128+e)*256+h]   (W = packed irfft basis)
//      Yp values are generated IN-REGISTER inside GEMM1 (fused softshrink), never materialized.
//  xn-part:   xn@F1s = hl@(tw2@F1s) + tb2@F1s,  F1s[t,h] = sum_e fw1
//  bias-part: x_noD@F1e,                        F1e[t,h] = sum_e (1+emb_e) fw1
//  s and x@F1e computed via hi/lo bf16 K-concat MFMA (A=[hi|lo|hi], B=[hi;hi;lo]).

typedef unsigned int uint;
typedef unsigned short ushort_t;
typedef __attribute__((ext_vector_type(4))) float f32x4;
typedef __attribute__((ext_vector_type(8))) short short8;

#define LAMBDA_ 0.001f
#define RSQRT512 0.044194173824159220f

__device__ __forceinline__ ushort_t f2bf(float f) {
    uint u = __float_as_uint(f);
    uint r = (u + 0x7FFFu + ((u >> 16) & 1u)) >> 16;
    return (ushort_t)r;
}
__device__ __forceinline__ float bf2f(ushort_t v) { return __uint_as_float(((uint)v) << 16); }
__device__ __forceinline__ float leaky_(float v) { return v >= 0.f ? v : 0.01f * v; }

// ---------------- K0: transpose x [8][512][64] -> A1cat [512 bn][1536] (hi|lo|hi) ----------------
__global__ __launch_bounds__(256) void k_transpose_x(const float* __restrict__ x, ushort_t* __restrict__ A1cat) {
    __shared__ float tile[32][33];
    int bid = blockIdx.x;             // 8 * 16 * 2 = 256
    int b = bid >> 5;
    int rem = bid & 31;
    int t0 = (rem >> 1) << 5;
    int n0 = (rem & 1) << 5;
    int tx = threadIdx.x & 31, ty = threadIdx.x >> 5;
    for (int i = 0; i < 4; ++i) {
        int tt = ty * 4 + i;
        tile[tt][tx] = x[(size_t)(b * 512 + t0 + tt) * 64 + n0 + tx];
    }
    __syncthreads();
    for (int i = 0; i < 4; ++i) {
        int nn = ty * 4 + i;
        float v = tile[tx][nn];
        ushort_t hi = f2bf(v);
        ushort_t lo = f2bf(v - bf2f(hi));
        size_t row = (size_t)(b * 64 + n0 + nn) * 1536;
        int t = t0 + tx;
        A1cat[row + t] = hi;
        A1cat[row + 512 + t] = lo;
        A1cat[row + 1024 + t] = hi;
    }
}

// ---------------- K1: setup — B1cat DFT rows, Wt, tw2_bf ----------------
__global__ __launch_bounds__(256) void k_setup(const float* __restrict__ tw2,
                                               ushort_t* __restrict__ B1cat, ushort_t* __restrict__ Wt,
                                               ushort_t* __restrict__ tw2_bf) {
    int bid = blockIdx.x;
    int region = bid >> 10;
    int id = ((bid & 1023) << 8) + threadIdx.x;
    int a = id >> 9, c = id & 511;
    if (region == 0) {       // B1cat rows 0-511: D[t=c][k=a]
        int f = (a <= 256) ? a : (a - 256);
        int m = (c * f) & 511;
        float ang = (float)m * (6.283185307179586f / 512.0f);
        float v = ((a <= 256) ? cosf(ang) : -sinf(ang)) * RSQRT512;
        ushort_t hi = f2bf(v);
        ushort_t lo = f2bf(v - bf2f(hi));
        size_t row = (size_t)a * 1536;
        B1cat[row + c] = hi;
        B1cat[row + 512 + c] = hi;
        B1cat[row + 1024 + c] = lo;
    } else if (region == 1) {  // Wt[k=a][t=c]
        int f = (a <= 256) ? a : (a - 256);
        int m = (c * f) & 511;
        float ang = (float)m * (6.283185307179586f / 512.0f);
        float v = ((a <= 256) ? cosf(ang) : -sinf(ang)) * RSQRT512;
        float sc = (a == 0 || a == 256) ? 1.0f : 2.0f;
        Wt[id] = f2bf(v * sc);
    } else {                   // tw2_bf: 512 blocks used
        if ((bid & 1023) < 512) tw2_bf[id] = f2bf(tw2[id]);
    }
}

// ---------------- K2: pack tw1 -> B1cat rows 512-767 (transposed, hi|hi|lo) ----------------
__global__ __launch_bounds__(256) void k_pack_tw1(const float* __restrict__ tw1, ushort_t* __restrict__ B1cat) {
    __shared__ float tile[64][65];
    int bid = blockIdx.x;            // 8 t-tiles * 4 h-tiles = 32
    int t0 = (bid & 7) << 6, h0 = (bid >> 3) << 6;
    int tid = threadIdx.x;
    for (int i = 0; i < 16; ++i) {
        int idx = tid + i * 256;
        int r = idx >> 6, cc = idx & 63;
        tile[r][cc] = tw1[(size_t)(t0 + r) * 256 + h0 + cc];
    }
    __syncthreads();
    for (int i = 0; i < 16; ++i) {
        int idx = tid + i * 256;
        int rr = idx >> 6, cc2 = idx & 63;      // rr: h, cc2: t
        float v = tile[cc2][rr];
        ushort_t hi = f2bf(v);
        ushort_t lo = f2bf(v - bf2f(hi));
        size_t row = (size_t)(512 + h0 + rr) * 1536;
        int t = t0 + cc2;
        B1cat[row + t] = hi;
        B1cat[row + 512 + t] = hi;
        B1cat[row + 1024 + t] = lo;
    }
}

// ---------------- K3: piecewise-linear tables (1 block); w2 staged in LDS ----------------
__global__ __launch_bounds__(256) void k_prep(const float* __restrict__ emb, const float* __restrict__ w1,
                                              const float* __restrict__ b1, const float* __restrict__ w2,
                                              const float* __restrict__ b2,
                                              ushort_t* __restrict__ Atab, ushort_t* __restrict__ Btab,
                                              float* __restrict__ bpkey_g) {
    __shared__ float w2s[256 * 128];   // 128 KB
    __shared__ float u_s[256], b1_s[256], key_s[256];
    __shared__ int idx_s[256];
    int tid = threadIdx.x;
    for (int i = 0; i < 32; ++i) {
        int idx4 = tid + i * 256;
        *(float4*)&w2s[idx4 * 4] = *(const float4*)&w2[idx4 * 4];
    }
    float acc = 0.f;
    for (int e = 0; e < 128; ++e) acc += emb[e] * w1[e * 256 + tid];
    u_s[tid] = acc;
    float bb0 = b1[tid];
    b1_s[tid] = bb0;
    key_s[tid] = (acc == 0.f) ? INFINITY : (-bb0 / acc);
    idx_s[tid] = tid;
    __syncthreads();
    for (int k = 2; k <= 256; k <<= 1) {
        for (int j = k >> 1; j > 0; j >>= 1) {
            int ixj = tid ^ j;
            if (ixj > tid) {
                bool up = ((tid & k) == 0);
                float a0 = key_s[tid], a1 = key_s[ixj];
                if ((a0 > a1) == up) {
                    key_s[tid] = a1; key_s[ixj] = a0;
                    int t0 = idx_s[tid]; idx_s[tid] = idx_s[ixj]; idx_s[ixj] = t0;
                }
            }
            __syncthreads();
        }
    }
    bpkey_g[tid] = key_s[tid];
    if (tid < 128) {
        int e = tid;
        float aA = 0.f, aB = 0.f;
        for (int h = 0; h < 256; ++h) {
            float uu = u_s[h], bbh = b1_s[h];
            float c = (uu < 0.f || (uu == 0.f && bbh >= 0.f)) ? 1.0f : 0.01f;
            float w = w2s[h * 128 + e];
            aA += c * uu * w;
            aB += c * bbh * w;
        }
        aB += b2[e];
        Atab[e] = f2bf(aA);
        Btab[e] = f2bf(aB);
        for (int r = 1; r <= 256; ++r) {
            int h = idx_s[r - 1];
            float uu = u_s[h], bbh = b1_s[h];
            float w = w2s[h * 128 + e];
            float sgn = (uu > 0.f) ? 0.99f : -0.99f;
            aA += sgn * uu * w;
            aB += sgn * bbh * w;
            Atab[r * 128 + e] = f2bf(aA);
            Btab[r * 128 + e] = f2bf(aB);
        }
    }
}

// ---------------- K4: transpose fw1 [(t,e)][h] f32 -> fw1T[(h*128+e)][t] bf16 ----------------
__global__ __launch_bounds__(256) void k_transpose_fw1(const float* __restrict__ fw1, ushort_t* __restrict__ fw1T) {
    __shared__ float tile[64][65];
    int bid = blockIdx.x;
    int e  = bid & 127;
    int hb = (bid >> 7) & 3;
    int tt = bid >> 9;
    int t0 = tt << 6, h0 = hb << 6;
    int tid = threadIdx.x;
    for (int i = 0; i < 4; ++i) {
        int idx = tid + i * 256;            // 0..1023 float4s
        int r = idx >> 4, c4 = idx & 15;
        const float* src = fw1 + ((size_t)(t0 + r) * 128 + e) * 256 + h0 + c4 * 4;
        float4 v = *(const float4*)src;
        tile[r][c4 * 4 + 0] = v.x;
        tile[r][c4 * 4 + 1] = v.y;
        tile[r][c4 * 4 + 2] = v.z;
        tile[r][c4 * 4 + 3] = v.w;
    }
    __syncthreads();
    for (int p = 0; p < 2; ++p) {
        int idx = tid + p * 256;            // 0..511 short8s
        int hh = idx >> 3, tg = idx & 7;
        short8 o;
        for (int j = 0; j < 8; ++j) o[j] = (short)f2bf(tile[tg * 8 + j][hh]);
        *(short8*)(fw1T + ((size_t)(h0 + hh) * 128 + e) * 512 + t0 + tg * 8) = o;
    }
}

// ---------------- K4b: F1 from fw1T: F1T[0][h][t]=sum_e fw1T, F1T[1][h][t]=sum_e(1+emb)fw1T ----------------
__global__ __launch_bounds__(256) void k_reduce_F2(const ushort_t* __restrict__ fw1T, const float* __restrict__ emb,
                                                   float* __restrict__ F1T) {
    __shared__ float embs[128];
    int h = blockIdx.x;                  // 256
    int tid = threadIdx.x;
    if (tid < 128) embs[tid] = 1.f + emb[tid];
    __syncthreads();
    int t2 = tid * 2;
    const ushort_t* base = fw1T + ((size_t)h << 16) + t2;
    float as0 = 0.f, as1 = 0.f, ae0 = 0.f, ae1 = 0.f;
#pragma unroll 4
    for (int e = 0; e < 128; ++e) {
        uint v = *(const uint*)(base + (size_t)e * 512);
        float v0 = bf2f((ushort_t)(v & 0xffff));
        float v1 = bf2f((ushort_t)(v >> 16));
        float w = embs[e];
        as0 += v0; as1 += v1;
        ae0 += w * v0; ae1 += w * v1;
    }
    F1T[(size_t)h * 512 + t2] = as0;
    F1T[(size_t)h * 512 + t2 + 1] = as1;
    F1T[131072 + (size_t)h * 512 + t2] = ae0;
    F1T[131072 + (size_t)h * 512 + t2 + 1] = ae1;
}

// ---------------- K5: pack F1s/F1e: B1cat rows 768-1023 (F1e hi|hi|lo), F1sT_bf, p2v = tb2@F1s ----------------
__global__ __launch_bounds__(64) void k_pack_F(const float* __restrict__ F1sT, const float* __restrict__ F1eT,
                                               const float* __restrict__ tb2,
                                               ushort_t* __restrict__ B1cat, ushort_t* __restrict__ F1sT_bf,
                                               float* __restrict__ p2v) {
    int h = blockIdx.x;                   // 256
    int lane = threadIdx.x;
    int t = lane * 8;
    float p2 = 0.f;
    short8 shi, ehi, elo;
    for (int j = 0; j < 8; ++j) {
        float vs = F1sT[(size_t)h * 512 + t + j];
        float ve = F1eT[(size_t)h * 512 + t + j];
        p2 += tb2[t + j] * vs;
        shi[j] = (short)f2bf(vs);
        ushort_t hi = f2bf(ve);
        ehi[j] = (short)hi;
        elo[j] = (short)f2bf(ve - bf2f(hi));
    }
    *(short8*)(F1sT_bf + (size_t)h * 512 + t) = shi;
    size_t row = (size_t)(768 + h) * 1536;
    *(short8*)(B1cat + row + t) = ehi;
    *(short8*)(B1cat + row + 512 + t) = ehi;
    *(short8*)(B1cat + row + 1024 + t) = elo;
    for (int o = 32; o > 0; o >>= 1) p2 += __shfl_xor(p2, o);
    if (lane == 0) p2v[h] = p2;
}

// ---------------- generic 128x128-tile bf16 MFMA GEMM with reg-prefetch; A [M][K] lda, B [N][K] ldb ----------------
template<int EPI>
__global__ __launch_bounds__(256) void k_mfma(const ushort_t* __restrict__ A, const ushort_t* __restrict__ Bm,
                                              int lda, int ldb, int kIters, int nTiles,
                                              void* __restrict__ C0, void* __restrict__ C1,
                                              void* __restrict__ C2, const float* __restrict__ aux) {
    __shared__ ushort_t shmem[2 * 128 * 72];
    ushort_t* As = shmem;
    ushort_t* Bs = shmem + 128 * 72;
    int tid = threadIdx.x;
    int lane = tid & 63, wid = tid >> 6;
    int wr = wid >> 1, wc = wid & 1;
    int bid = blockIdx.x;
    int mt, nt;
    if (EPI == 0) {
        int xx = bid & 7, y = bid >> 3;
        mt = y & 3;
        nt = ((y >> 2) << 3) | xx;
    } else {
        nt = bid % nTiles;
        mt = bid / nTiles;
    }
    int m0 = mt * 128, n0 = nt * 128;
    f32x4 acc[4][4] = {};
    uint4 va[4], vb[4];
    auto issue = [&](int kt) {
        int kb = kt * 64;
        for (int i = 0; i < 4; ++i) {
            int q = tid + i * 256;
            int row = q >> 3, kcc = (q & 7) << 3;
            va[i] = *(const uint4*)(A + (size_t)(m0 + row) * lda + kb + kcc);
            vb[i] = *(const uint4*)(Bm + (size_t)(n0 + row) * ldb + kb + kcc);
        }
    };
    issue(0);
    for (int kt = 0; kt < kIters; ++kt) {
        if (kt > 0) __syncthreads();
        for (int i = 0; i < 4; ++i) {
            int q = tid + i * 256;
            int row = q >> 3, kcc = (q & 7) << 3;
            *(uint4*)&As[row * 72 + kcc] = va[i];
            *(uint4*)&Bs[row * 72 + kcc] = vb[i];
        }
        __syncthreads();
        if (kt + 1 < kIters) issue(kt + 1);
        for (int ks = 0; ks < 2; ++ks) {
            short8 a[4], b[4];
            int kk = ks * 32 + (lane >> 4) * 8;
            for (int mi = 0; mi < 4; ++mi)
                a[mi] = *(const short8*)&As[(wr * 64 + mi * 16 + (lane & 15)) * 72 + kk];
            for (int ni = 0; ni < 4; ++ni)
                b[ni] = *(const short8*)&Bs[(wc * 64 + ni * 16 + (lane & 15)) * 72 + kk];
            for (int mi = 0; mi < 4; ++mi)
                for (int ni = 0; ni < 4; ++ni)
                    acc[mi][ni] = __builtin_amdgcn_mfma_f32_16x16x32_bf16(a[mi], b[ni], acc[mi][ni], 0, 0, 0);
        }
    }
    if (EPI == 0) {
        __syncthreads();
        for (int mi = 0; mi < 4; ++mi) {
            int ml = wr * 64 + mi * 16 + ((lane >> 4) << 2);
            for (int ni = 0; ni < 4; ++ni) {
                int nl = wc * 64 + ni * 16 + (lane & 15);
                for (int r = 0; r < 4; ++r)
                    shmem[(ml + r) * 128 + nl] = f2bf(acc[mi][ni][r]);
            }
        }
        __syncthreads();
        short8* d8 = (short8*)((ushort_t*)C0 + ((size_t)(n0 >> 7) << 16) + (size_t)m0 * 128);
        const short8* s8 = (const short8*)shmem;
        for (int i = 0; i < 8; ++i) d8[tid + i * 256] = s8[tid + i * 256];
        return;
    }
    int mb0 = m0 + wr * 64 + ((lane >> 4) << 2);
    int nb0 = n0 + wc * 64 + (lane & 15);
    for (int mi = 0; mi < 4; ++mi) {
        for (int ni = 0; ni < 4; ++ni) {
            int mbase = mb0 + mi * 16;
            int n = nb0 + ni * 16;
            if (EPI == 2) {
                float* s = (float*)C0;
                ushort_t* hl = (ushort_t*)C1;
                float* h2c = (float*)C2;
                for (int r = 0; r < 4; ++r) {
                    int m = mbase + r;
                    float v = acc[mi][ni][r];
                    if (n < 512) s[(size_t)m * 512 + n] = v;
                    else if (n < 768) hl[(size_t)m * 256 + (n - 512)] = f2bf(leaky_(v + aux[n - 512]));
                    else h2c[(size_t)m * 256 + (n - 768)] = v;
                }
            } else if (EPI == 4) {
                ushort_t* P2T = (ushort_t*)C0;
                ushort4 o;
                o.x = f2bf(acc[mi][ni][0]);
                o.y = f2bf(acc[mi][ni][1]);
                o.z = f2bf(acc[mi][ni][2]);
                o.w = f2bf(acc[mi][ni][3]);
                *(ushort4*)(P2T + (size_t)n * 256 + mbase) = o;
            } else if (EPI == 5) {
                float* h2b = (float*)C0;
                const float* h2c = (const float*)C1;
                for (int r = 0; r < 4; ++r) {
                    int m = mbase + r;
                    h2b[(size_t)m * 256 + n] = acc[mi][ni][r] + aux[n] + h2c[(size_t)m * 256 + n];
                }
            }
        }
    }
}

// ---------------- GEMM1 (fused): partial[kc] = cook(s) @ M2T^T chunk ----------------
// M=512, N=256, K=65536. BM=128, BN=128, split-K 64 chunks of 1024 (8 k-values x 128 e).
// A-tile values generated in-register: softshrink(s*Atab[r]+Btab[r]) -> bf16. No Yp in memory.
// grid 512 = xcd(8) x [nt(2) x mt(4) x kcl(8)]; 8 blocks of one k-group share L2 chunks per XCD.
__global__ __launch_bounds__(512, 4) void k_gemm1(const float* __restrict__ s,
                                                  const ushort_t* __restrict__ Atab, const ushort_t* __restrict__ Btab,
                                                  const float* __restrict__ bpkey,
                                                  const ushort_t* __restrict__ Bm,
                                                  float* __restrict__ partial) {
    __shared__ ushort_t As[128 * 72];
    __shared__ ushort_t Bs[128 * 72];
    __shared__ float sv_s[1024];
    __shared__ ushort_t r_s[1024];
    __shared__ float bp_s[256];
    int tid = threadIdx.x;
    int lane = tid & 63, wid = tid >> 6;
    int wr = wid >> 2, wc = wid & 3;           // 2 x 4 waves; wave tile 64m x 32n
    int bid = blockIdx.x;
    int xcd = bid & 7, j = bid >> 3;
    int nt = j & 1, mt = (j >> 1) & 3, kcl = j >> 3;
    int kc = xcd * 8 + kcl;                    // 0..63
    int m0 = mt * 128, n0 = nt * 128;
    size_t k0 = (size_t)kc * 1024;
    if (tid < 256) bp_s[tid] = bpkey[tid];
    __syncthreads();
    if (tid < 256) {   // stage s-slice (128 rows x 8 k): 256 thr x float4 = exactly 1024 vals
        int row = tid >> 1, j4 = (tid & 1) * 4;
        float4 sv4 = *(const float4*)(s + (size_t)(m0 + row) * 512 + kc * 8 + j4);
        float svv[4] = {sv4.x, sv4.y, sv4.z, sv4.w};
        ushort_t rr[4];
        for (int q = 0; q < 4; ++q) {
            float sv = svv[q];
            int lo = 0, hi = 256;
            while (lo < hi) { int mid = (lo + hi) >> 1; if (bp_s[mid] <= sv) lo = mid + 1; else hi = mid; }
            rr[q] = (ushort_t)lo;
        }
        *(float4*)&sv_s[row * 8 + j4] = sv4;
        r_s[row * 8 + j4 + 0] = rr[0];
        r_s[row * 8 + j4 + 1] = rr[1];
        r_s[row * 8 + j4 + 2] = rr[2];
        r_s[row * 8 + j4 + 3] = rr[3];
    }
    __syncthreads();

    f32x4 acc[4][2] = {};
    short8 ta[2], tb[2], aval[2];
    uint4 vb[2];
    float svr[2];
    auto issue = [&](int kt) {
        int kl = kt >> 1;
        for (int i = 0; i < 2; ++i) {
            int q = tid + i * 512;
            int row = q >> 3, kcc = (q & 7) << 3;
            int e0 = ((kt & 1) << 6) + kcc;
            float sv = sv_s[row * 8 + kl];
            int r = r_s[row * 8 + kl];
            svr[i] = sv;
            ta[i] = *(const short8*)(Atab + r * 128 + e0);
            tb[i] = *(const short8*)(Btab + r * 128 + e0);
            vb[i] = *(const uint4*)(Bm + (size_t)(n0 + row) * 65536 + k0 + kt * 64 + kcc);
        }
    };
    auto cook = [&]() {
        for (int i = 0; i < 2; ++i) {
            float sv = svr[i];
            short8 o;
            for (int jj = 0; jj < 8; ++jj) {
                float y = fmaf(sv, bf2f((ushort_t)ta[i][jj]), bf2f((ushort_t)tb[i][jj]));
                y = y - fminf(fmaxf(y, -LAMBDA_), LAMBDA_);
                o[jj] = (short)f2bf(y);
            }
            aval[i] = o;
        }
    };
    issue(0);
    cook();
    for (int kt = 0; kt < 16; ++kt) {
        if (kt > 0) __syncthreads();
        for (int i = 0; i < 2; ++i) {
            int q = tid + i * 512;
            int row = q >> 3, kcc = (q & 7) << 3;
            *(short8*)&As[row * 72 + kcc] = aval[i];
            *(uint4*)&Bs[row * 72 + kcc] = vb[i];
        }
        __syncthreads();
        if (kt + 1 < 16) issue(kt + 1);
        for (int ks = 0; ks < 2; ++ks) {
            short8 a[4], b[2];
            int kk = ks * 32 + (lane >> 4) * 8;
            for (int mi = 0; mi < 4; ++mi)
                a[mi] = *(const short8*)&As[(wr * 64 + mi * 16 + (lane & 15)) * 72 + kk];
            for (int ni = 0; ni < 2; ++ni)
                b[ni] = *(const short8*)&Bs[(wc * 32 + ni * 16 + (lane & 15)) * 72 + kk];
            for (int mi = 0; mi < 4; ++mi)
                for (int ni = 0; ni < 2; ++ni)
                    acc[mi][ni] = __builtin_amdgcn_mfma_f32_16x16x32_bf16(a[mi], b[ni], acc[mi][ni], 0, 0, 0);
        }
        if (kt + 1 < 16) cook();
    }
    int mb0 = m0 + wr * 64 + ((lane >> 4) << 2);
    int nb0 = n0 + wc * 32 + (lane & 15);
    float* pbase = partial + (size_t)kc * 131072;
    for (int mi = 0; mi < 4; ++mi)
        for (int ni = 0; ni < 2; ++ni) {
            int mbase = mb0 + mi * 16;
            int n = nb0 + ni * 16;
            for (int r = 0; r < 4; ++r)
                pbase[(size_t)(mbase + r) * 256 + n] = acc[mi][ni][r];
        }
}

// ---------------- K10: final: a = leaky(sum_kc partial + h2b + fb1); out = a@fw2+fb2 ----------------
__global__ __launch_bounds__(128) void k_final(const float* __restrict__ partial, const float* __restrict__ h2b,
                                               const float* __restrict__ fb1,
                                               const float* __restrict__ fw2, const float* __restrict__ fb2,
                                               float* __restrict__ out) {
    __shared__ float a_s[256];
    int bn = blockIdx.x;
    int tid = threadIdx.x;
    for (int i = tid; i < 256; i += 128) {
        float acc = h2b[(size_t)bn * 256 + i] + fb1[i];
#pragma unroll 8
        for (int kc = 0; kc < 64; ++kc)
            acc += partial[((size_t)kc * 512 + bn) * 256 + i];
        a_s[i] = leaky_(acc);
    }
    __syncthreads();
    if (tid < 96) {
        float acc = fb2[tid];
        for (int hh = 0; hh < 256; ++hh)
            acc += a_s[hh] * fw2[hh * 96 + tid];
        int b = bn >> 6, n = bn & 63;
        out[(size_t)(b * 96 + tid) * 64 + n] = acc;
    }
}

extern "C" void kernel_launch(void* const* d_in, const int* in_sizes, int n_in,
                              void* d_out, int out_size, void* d_ws, size_t ws_size,
                              hipStream_t stream) {
    const float* x   = (const float*)d_in[0];
    const float* emb = (const float*)d_in[1];
    const float* w1  = (const float*)d_in[2];
    const float* b1  = (const float*)d_in[3];
    const float* w2  = (const float*)d_in[4];
    const float* b2  = (const float*)d_in[5];
    const float* tw1 = (const float*)d_in[6];
    const float* tb1 = (const float*)d_in[7];
    const float* tw2 = (const float*)d_in[8];
    const float* tb2 = (const float*)d_in[9];
    const float* fw1 = (const float*)d_in[10];
    const float* fb1 = (const float*)d_in[11];
    const float* fw2 = (const float*)d_in[12];
    const float* fb2 = (const float*)d_in[13];
    float* out = (float*)d_out;

    char* W = (char*)d_ws;
    size_t off = 0;
    auto take = [&](size_t bytes) { size_t r = off; off += (bytes + 255) & ~(size_t)255; return r; };
    ushort_t* fw1T  = (ushort_t*)(W + take(33554432));       // [32768 j''=h*128+e][512 t] bf16
    ushort_t* M2T   = (ushort_t*)(W + take(33554432));       // [256 h][65536 k'] bf16
    float* partial  = (float*)(W + take(64 * 512 * 256 * 4)); // [64 kc][512 bn][256 h] f32
    ushort_t* A1cat = (ushort_t*)(W + take(512 * 1536 * 2));
    ushort_t* B1cat = (ushort_t*)(W + take(1024 * 1536 * 2));
    ushort_t* Wt    = (ushort_t*)(W + take(512 * 512 * 2));
    ushort_t* tw2bf = (ushort_t*)(W + take(256 * 512 * 2));
    float* F1T      = (float*)(W + take(2 * 256 * 512 * 4)); // [2][h][t]
    ushort_t* F1sbf = (ushort_t*)(W + take(256 * 512 * 2));
    float* sbuf     = (float*)(W + take(512 * 512 * 4));
    ushort_t* hlbuf = (ushort_t*)(W + take(512 * 256 * 2));
    float* h2c      = (float*)(W + take(512 * 256 * 4));
    ushort_t* P2T   = (ushort_t*)(W + take(256 * 256 * 2));
    float* p2v      = (float*)(W + take(256 * 4));
    ushort_t* Atab  = (ushort_t*)(W + take(257 * 128 * 2));
    ushort_t* Btab  = (ushort_t*)(W + take(257 * 128 * 2));
    float* bpkey    = (float*)(W + take(256 * 4));
    float* h2b      = (float*)(W + take(512 * 256 * 4));
    (void)ws_size; (void)in_sizes; (void)n_in; (void)out_size;

    k_setup<<<3072, 256, 0, stream>>>(tw2, B1cat, Wt, tw2bf);
    k_pack_tw1<<<32, 256, 0, stream>>>(tw1, B1cat);
    k_transpose_x<<<256, 256, 0, stream>>>(x, A1cat);
    k_prep<<<1, 256, 0, stream>>>(emb, w1, b1, w2, b2, Atab, Btab, bpkey);
    k_transpose_fw1<<<4096, 256, 0, stream>>>(fw1, fw1T);
    k_reduce_F2<<<256, 256, 0, stream>>>(fw1T, emb, F1T);
    k_pack_F<<<256, 64, 0, stream>>>(F1T, F1T + 131072, tb2, B1cat, F1sbf, p2v);
    // G1: [s | hl | h2c] = xTcat @ B1cat^T   (M=512, N=1024, K=1536 hi/lo)
    k_mfma<2><<<32, 256, 0, stream>>>(A1cat, B1cat, 1536, 1536, 24, 8, sbuf, hlbuf, h2c, tb1);
    // GEMM0: M2T = Wt @ fw1T^T  (M=512 k, N=32768 j'', K=512 t)
    k_mfma<0><<<1024, 256, 0, stream>>>(Wt, fw1T, 512, 512, 8, 256, M2T, nullptr, nullptr, nullptr);
    // P2' = tw2 @ F1s  (M=256 h'', N=256 h', K=512 t) -> P2T
    k_mfma<4><<<4, 256, 0, stream>>>(tw2bf, F1sbf, 512, 512, 8, 2, P2T, nullptr, nullptr, nullptr);
    // GEMM1 (fused softshrink-A): partial[kc] = cook(s) @ M2T^T
    k_gemm1<<<512, 512, 0, stream>>>(sbuf, Atab, Btab, bpkey, M2T, partial);
    // h2b = hl @ P2'^T + p2v + h2c  (M=512, N=256, K=256)
    k_mfma<5><<<8, 256, 0, stream>>>(hlbuf, P2T, 256, 256, 4, 2, h2b, h2c, nullptr, p2v);
    k_final<<<512, 128, 0, stream>>>(partial, h2b, fb1, fw2, fb2, out);
}

// Round 7
// 244.073 us; speedup vs baseline: 1.3527x; 1.3527x over previous
//
#include <hip/hip_runtime.h>
#include <hip/hip_bf16.h>

// B=8, T=512, N=64, E=128, H=256, P=96.  bn = b*64+n (512 rows).
// Identities:
//  xe = x_noD*emb  => rfft factorizes: spectral scalar s[bn,k] (packed: k<=256 real, k>256 imag)
//  mlp(s*emb) piecewise-linear in s (257 regions; tables Atab/Btab[r][e])
//  xt-part of flat@fw1:  h2[bn,h] = sum_{k,e} Yp[bn,k,e] * M2[k,e,h],
//      M2[k,(h,e)] = sum_t W[t,k] fw1[(t*128+e)*256+h]   (W = packed irfft basis)
//      Yp values are generated IN-REGISTER inside GEMM1 (fused softshrink), never materialized.
//  xn-part:   xn@F1s = hl@(tw2@F1s) + tb2@F1s,  F1s[t,h] = sum_e fw1
//  bias-part: x_noD@F1e,                        F1e[t,h] = sum_e (1+emb_e) fw1
//  s and x@F1e computed via hi/lo bf16 K-concat MFMA (A=[hi|lo|hi], B=[hi;hi;lo]).

typedef unsigned int uint;
typedef unsigned short ushort_t;
typedef __attribute__((ext_vector_type(4))) float f32x4;
typedef __attribute__((ext_vector_type(8))) short short8;

#define LAMBDA_ 0.001f
#define RSQRT512 0.044194173824159220f

__device__ __forceinline__ ushort_t f2bf(float f) {
    uint u = __float_as_uint(f);
    uint r = (u + 0x7FFFu + ((u >> 16) & 1u)) >> 16;
    return (ushort_t)r;
}
__device__ __forceinline__ float bf2f(ushort_t v) { return __uint_as_float(((uint)v) << 16); }
__device__ __forceinline__ float leaky_(float v) { return v >= 0.f ? v : 0.01f * v; }

// ---------------- K0: transpose x [8][512][64] -> A1cat [512 bn][1536] (hi|lo|hi) ----------------
__global__ __launch_bounds__(256) void k_transpose_x(const float* __restrict__ x, ushort_t* __restrict__ A1cat) {
    __shared__ float tile[32][33];
    int bid = blockIdx.x;             // 8 * 16 * 2 = 256
    int b = bid >> 5;
    int rem = bid & 31;
    int t0 = (rem >> 1) << 5;
    int n0 = (rem & 1) << 5;
    int tx = threadIdx.x & 31, ty = threadIdx.x >> 5;
    for (int i = 0; i < 4; ++i) {
        int tt = ty * 4 + i;
        tile[tt][tx] = x[(size_t)(b * 512 + t0 + tt) * 64 + n0 + tx];
    }
    __syncthreads();
    for (int i = 0; i < 4; ++i) {
        int nn = ty * 4 + i;
        float v = tile[tx][nn];
        ushort_t hi = f2bf(v);
        ushort_t lo = f2bf(v - bf2f(hi));
        size_t row = (size_t)(b * 64 + n0 + nn) * 1536;
        int t = t0 + tx;
        A1cat[row + t] = hi;
        A1cat[row + 512 + t] = lo;
        A1cat[row + 1024 + t] = hi;
    }
}

// ---------------- K1: setup — B1cat DFT rows, Wt, tw2_bf ----------------
__global__ __launch_bounds__(256) void k_setup(const float* __restrict__ tw2,
                                               ushort_t* __restrict__ B1cat, ushort_t* __restrict__ Wt,
                                               ushort_t* __restrict__ tw2_bf) {
    int bid = blockIdx.x;
    int region = bid >> 10;
    int id = ((bid & 1023) << 8) + threadIdx.x;
    int a = id >> 9, c = id & 511;
    if (region == 0) {       // B1cat rows 0-511: D[t=c][k=a]
        int f = (a <= 256) ? a : (a - 256);
        int m = (c * f) & 511;
        float ang = (float)m * (6.283185307179586f / 512.0f);
        float v = ((a <= 256) ? cosf(ang) : -sinf(ang)) * RSQRT512;
        ushort_t hi = f2bf(v);
        ushort_t lo = f2bf(v - bf2f(hi));
        size_t row = (size_t)a * 1536;
        B1cat[row + c] = hi;
        B1cat[row + 512 + c] = hi;
        B1cat[row + 1024 + c] = lo;
    } else if (region == 1) {  // Wt[k=a][t=c]
        int f = (a <= 256) ? a : (a - 256);
        int m = (c * f) & 511;
        float ang = (float)m * (6.283185307179586f / 512.0f);
        float v = ((a <= 256) ? cosf(ang) : -sinf(ang)) * RSQRT512;
        float sc = (a == 0 || a == 256) ? 1.0f : 2.0f;
        Wt[id] = f2bf(v * sc);
    } else {                   // tw2_bf: 512 blocks used
        if ((bid & 1023) < 512) tw2_bf[id] = f2bf(tw2[id]);
    }
}

// ---------------- K2: pack tw1 -> B1cat rows 512-767 (transposed, hi|hi|lo) ----------------
__global__ __launch_bounds__(256) void k_pack_tw1(const float* __restrict__ tw1, ushort_t* __restrict__ B1cat) {
    __shared__ float tile[64][65];
    int bid = blockIdx.x;            // 8 t-tiles * 4 h-tiles = 32
    int t0 = (bid & 7) << 6, h0 = (bid >> 3) << 6;
    int tid = threadIdx.x;
    for (int i = 0; i < 16; ++i) {
        int idx = tid + i * 256;
        int r = idx >> 6, cc = idx & 63;
        tile[r][cc] = tw1[(size_t)(t0 + r) * 256 + h0 + cc];
    }
    __syncthreads();
    for (int i = 0; i < 16; ++i) {
        int idx = tid + i * 256;
        int rr = idx >> 6, cc2 = idx & 63;      // rr: h, cc2: t
        float v = tile[cc2][rr];
        ushort_t hi = f2bf(v);
        ushort_t lo = f2bf(v - bf2f(hi));
        size_t row = (size_t)(512 + h0 + rr) * 1536;
        int t = t0 + cc2;
        B1cat[row + t] = hi;
        B1cat[row + 512 + t] = hi;
        B1cat[row + 1024 + t] = lo;
    }
}

// ---------------- K3: piecewise-linear tables (1 block); w2 staged in LDS ----------------
__global__ __launch_bounds__(256) void k_prep(const float* __restrict__ emb, const float* __restrict__ w1,
                                              const float* __restrict__ b1, const float* __restrict__ w2,
                                              const float* __restrict__ b2,
                                              ushort_t* __restrict__ Atab, ushort_t* __restrict__ Btab,
                                              float* __restrict__ bpkey_g) {
    __shared__ float w2s[256 * 128];   // 128 KB
    __shared__ float u_s[256], b1_s[256], key_s[256];
    __shared__ int idx_s[256];
    int tid = threadIdx.x;
    for (int i = 0; i < 32; ++i) {
        int idx4 = tid + i * 256;
        *(float4*)&w2s[idx4 * 4] = *(const float4*)&w2[idx4 * 4];
    }
    float acc = 0.f;
    for (int e = 0; e < 128; ++e) acc += emb[e] * w1[e * 256 + tid];
    u_s[tid] = acc;
    float bb0 = b1[tid];
    b1_s[tid] = bb0;
    key_s[tid] = (acc == 0.f) ? INFINITY : (-bb0 / acc);
    idx_s[tid] = tid;
    __syncthreads();
    for (int k = 2; k <= 256; k <<= 1) {
        for (int j = k >> 1; j > 0; j >>= 1) {
            int ixj = tid ^ j;
            if (ixj > tid) {
                bool up = ((tid & k) == 0);
                float a0 = key_s[tid], a1 = key_s[ixj];
                if ((a0 > a1) == up) {
                    key_s[tid] = a1; key_s[ixj] = a0;
                    int t0 = idx_s[tid]; idx_s[tid] = idx_s[ixj]; idx_s[ixj] = t0;
                }
            }
            __syncthreads();
        }
    }
    bpkey_g[tid] = key_s[tid];
    if (tid < 128) {
        int e = tid;
        float aA = 0.f, aB = 0.f;
        for (int h = 0; h < 256; ++h) {
            float uu = u_s[h], bbh = b1_s[h];
            float c = (uu < 0.f || (uu == 0.f && bbh >= 0.f)) ? 1.0f : 0.01f;
            float w = w2s[h * 128 + e];
            aA += c * uu * w;
            aB += c * bbh * w;
        }
        aB += b2[e];
        Atab[e] = f2bf(aA);
        Btab[e] = f2bf(aB);
        for (int r = 1; r <= 256; ++r) {
            int h = idx_s[r - 1];
            float uu = u_s[h], bbh = b1_s[h];
            float w = w2s[h * 128 + e];
            float sgn = (uu > 0.f) ? 0.99f : -0.99f;
            aA += sgn * uu * w;
            aB += sgn * bbh * w;
            Atab[r * 128 + e] = f2bf(aA);
            Btab[r * 128 + e] = f2bf(aB);
        }
    }
}

// ---------------- K4: transpose fw1 [(t,e)][h] f32 -> fw1T[(h*128+e)][t] bf16 ----------------
__global__ __launch_bounds__(256) void k_transpose_fw1(const float* __restrict__ fw1, ushort_t* __restrict__ fw1T) {
    __shared__ float tile[64][65];
    int bid = blockIdx.x;
    int e  = bid & 127;
    int hb = (bid >> 7) & 3;
    int tt = bid >> 9;
    int t0 = tt << 6, h0 = hb << 6;
    int tid = threadIdx.x;
    for (int i = 0; i < 4; ++i) {
        int idx = tid + i * 256;            // 0..1023 float4s
        int r = idx >> 4, c4 = idx & 15;
        const float* src = fw1 + ((size_t)(t0 + r) * 128 + e) * 256 + h0 + c4 * 4;
        float4 v = *(const float4*)src;
        tile[r][c4 * 4 + 0] = v.x;
        tile[r][c4 * 4 + 1] = v.y;
        tile[r][c4 * 4 + 2] = v.z;
        tile[r][c4 * 4 + 3] = v.w;
    }
    __syncthreads();
    for (int p = 0; p < 2; ++p) {
        int idx = tid + p * 256;            // 0..511 short8s
        int hh = idx >> 3, tg = idx & 7;
        short8 o;
        for (int j = 0; j < 8; ++j) o[j] = (short)f2bf(tile[tg * 8 + j][hh]);
        *(short8*)(fw1T + ((size_t)(h0 + hh) * 128 + e) * 512 + t0 + tg * 8) = o;
    }
}

// ---------------- K4b: F1 from fw1T: F1T[0][h][t]=sum_e fw1T, F1T[1][h][t]=sum_e(1+emb)fw1T ----------------
__global__ __launch_bounds__(256) void k_reduce_F2(const ushort_t* __restrict__ fw1T, const float* __restrict__ emb,
                                                   float* __restrict__ F1T) {
    __shared__ float embs[128];
    int h = blockIdx.x;                  // 256
    int tid = threadIdx.x;
    if (tid < 128) embs[tid] = 1.f + emb[tid];
    __syncthreads();
    int t2 = tid * 2;
    const ushort_t* base = fw1T + ((size_t)h << 16) + t2;
    float as0 = 0.f, as1 = 0.f, ae0 = 0.f, ae1 = 0.f;
#pragma unroll 4
    for (int e = 0; e < 128; ++e) {
        uint v = *(const uint*)(base + (size_t)e * 512);
        float v0 = bf2f((ushort_t)(v & 0xffff));
        float v1 = bf2f((ushort_t)(v >> 16));
        float w = embs[e];
        as0 += v0; as1 += v1;
        ae0 += w * v0; ae1 += w * v1;
    }
    F1T[(size_t)h * 512 + t2] = as0;
    F1T[(size_t)h * 512 + t2 + 1] = as1;
    F1T[131072 + (size_t)h * 512 + t2] = ae0;
    F1T[131072 + (size_t)h * 512 + t2 + 1] = ae1;
}

// ---------------- K5: pack F1s/F1e: B1cat rows 768-1023 (F1e hi|hi|lo), F1sT_bf, p2v = tb2@F1s ----------------
__global__ __launch_bounds__(64) void k_pack_F(const float* __restrict__ F1sT, const float* __restrict__ F1eT,
                                               const float* __restrict__ tb2,
                                               ushort_t* __restrict__ B1cat, ushort_t* __restrict__ F1sT_bf,
                                               float* __restrict__ p2v) {
    int h = blockIdx.x;                   // 256
    int lane = threadIdx.x;
    int t = lane * 8;
    float p2 = 0.f;
    short8 shi, ehi, elo;
    for (int j = 0; j < 8; ++j) {
        float vs = F1sT[(size_t)h * 512 + t + j];
        float ve = F1eT[(size_t)h * 512 + t + j];
        p2 += tb2[t + j] * vs;
        shi[j] = (short)f2bf(vs);
        ushort_t hi = f2bf(ve);
        ehi[j] = (short)hi;
        elo[j] = (short)f2bf(ve - bf2f(hi));
    }
    *(short8*)(F1sT_bf + (size_t)h * 512 + t) = shi;
    size_t row = (size_t)(768 + h) * 1536;
    *(short8*)(B1cat + row + t) = ehi;
    *(short8*)(B1cat + row + 512 + t) = ehi;
    *(short8*)(B1cat + row + 1024 + t) = elo;
    for (int o = 32; o > 0; o >>= 1) p2 += __shfl_xor(p2, o);
    if (lane == 0) p2v[h] = p2;
}

// ---------------- generic 128x128-tile bf16 MFMA GEMM (round-4 loop structure); A [M][K] lda, B [N][K] ldb ----------------
// EPI 0: M2T contiguous tile store via XOR-swizzled LDS staging (grid 1024)
// EPI 2: G1: s f32 / hl bf16(leaky+tb1) / h2c f32 split by n  (grid 32)
// EPI 4: P2T transposed bf16 store (grid 4)
// EPI 5: h2b = acc + p2v[n] + h2c (grid 8)
template<int EPI>
__global__ __launch_bounds__(256) void k_mfma(const ushort_t* __restrict__ A, const ushort_t* __restrict__ Bm,
                                              int lda, int ldb, int kIters, int nTiles,
                                              void* __restrict__ C0, void* __restrict__ C1,
                                              void* __restrict__ C2, const float* __restrict__ aux) {
    __shared__ ushort_t shmem[2 * 128 * 72];
    ushort_t* As = shmem;
    ushort_t* Bs = shmem + 128 * 72;
    int tid = threadIdx.x;
    int lane = tid & 63, wid = tid >> 6;
    int wr = wid >> 1, wc = wid & 1;
    int bid = blockIdx.x;
    int mt, nt;
    if (EPI == 0) {
        int xx = bid & 7, y = bid >> 3;
        mt = y & 3;
        nt = ((y >> 2) << 3) | xx;
    } else {
        nt = bid % nTiles;
        mt = bid / nTiles;
    }
    int m0 = mt * 128, n0 = nt * 128;
    f32x4 acc[4][4] = {};
    for (int kt = 0; kt < kIters; ++kt) {
        int kb = kt * 64;
        __syncthreads();
        {
            uint4 va[4], vb[4];
            for (int i = 0; i < 4; ++i) {
                int q = tid + i * 256;
                int row = q >> 3, kcc = (q & 7) << 3;
                va[i] = *(const uint4*)(A + (size_t)(m0 + row) * lda + kb + kcc);
                vb[i] = *(const uint4*)(Bm + (size_t)(n0 + row) * ldb + kb + kcc);
            }
            for (int i = 0; i < 4; ++i) {
                int q = tid + i * 256;
                int row = q >> 3, kcc = (q & 7) << 3;
                *(uint4*)&As[row * 72 + kcc] = va[i];
                *(uint4*)&Bs[row * 72 + kcc] = vb[i];
            }
        }
        __syncthreads();
        for (int ks = 0; ks < 2; ++ks) {
            short8 a[4], b[4];
            int kk = ks * 32 + (lane >> 4) * 8;
            for (int mi = 0; mi < 4; ++mi)
                a[mi] = *(const short8*)&As[(wr * 64 + mi * 16 + (lane & 15)) * 72 + kk];
            for (int ni = 0; ni < 4; ++ni)
                b[ni] = *(const short8*)&Bs[(wc * 64 + ni * 16 + (lane & 15)) * 72 + kk];
            for (int mi = 0; mi < 4; ++mi)
                for (int ni = 0; ni < 4; ++ni)
                    acc[mi][ni] = __builtin_amdgcn_mfma_f32_16x16x32_bf16(a[mi], b[ni], acc[mi][ni], 0, 0, 0);
        }
    }
    if (EPI == 0) {
        // stage C tile (128x128 bf16 = one contiguous 32KB chunk of M2T) in LDS with XOR swizzle,
        // then linear short8 copy (swizzle-aware read).
        __syncthreads();
        for (int mi = 0; mi < 4; ++mi) {
            int ml = wr * 64 + mi * 16 + ((lane >> 4) << 2);
            for (int ni = 0; ni < 4; ++ni) {
                int nl = wc * 64 + ni * 16 + (lane & 15);
                for (int r = 0; r < 4; ++r) {
                    int row = ml + r;
                    shmem[row * 128 + (nl ^ ((row & 7) << 4))] = f2bf(acc[mi][ni][r]);
                }
            }
        }
        __syncthreads();
        short8* d8 = (short8*)((ushort_t*)C0 + ((size_t)(n0 >> 7) << 16) + (size_t)m0 * 128);
        for (int i = 0; i < 8; ++i) {
            int p = tid + i * 256;                 // short8 index 0..2047
            int row = p >> 4;
            int col0 = (p & 15) * 8;
            d8[p] = *(const short8*)&shmem[row * 128 + (col0 ^ ((row & 7) << 4))];
        }
        return;
    }
    int mb0 = m0 + wr * 64 + ((lane >> 4) << 2);
    int nb0 = n0 + wc * 64 + (lane & 15);
    for (int mi = 0; mi < 4; ++mi) {
        for (int ni = 0; ni < 4; ++ni) {
            int mbase = mb0 + mi * 16;
            int n = nb0 + ni * 16;
            if (EPI == 2) {
                float* s = (float*)C0;
                ushort_t* hl = (ushort_t*)C1;
                float* h2c = (float*)C2;
                for (int r = 0; r < 4; ++r) {
                    int m = mbase + r;
                    float v = acc[mi][ni][r];
                    if (n < 512) s[(size_t)m * 512 + n] = v;
                    else if (n < 768) hl[(size_t)m * 256 + (n - 512)] = f2bf(leaky_(v + aux[n - 512]));
                    else h2c[(size_t)m * 256 + (n - 768)] = v;
                }
            } else if (EPI == 4) {
                ushort_t* P2T = (ushort_t*)C0;
                ushort4 o;
                o.x = f2bf(acc[mi][ni][0]);
                o.y = f2bf(acc[mi][ni][1]);
                o.z = f2bf(acc[mi][ni][2]);
                o.w = f2bf(acc[mi][ni][3]);
                *(ushort4*)(P2T + (size_t)n * 256 + mbase) = o;
            } else if (EPI == 5) {
                float* h2b = (float*)C0;
                const float* h2c = (const float*)C1;
                for (int r = 0; r < 4; ++r) {
                    int m = mbase + r;
                    h2b[(size_t)m * 256 + n] = acc[mi][ni][r] + aux[n] + h2c[(size_t)m * 256 + n];
                }
            }
        }
    }
}

// ---------------- GEMM1 (fused): partial[kc] = cook(s) @ M2T^T chunk ----------------
// M=512, N=256, K=65536. BM=128, BN=128, split-K 32 chunks of 2048 (16 k-values x 128 e).
// A-tile values generated in-register: softshrink(s*Atab[r]+Btab[r]) -> bf16. No Yp in memory.
// grid 256 = xcd(8) x [nt(2) x mt(4) x kcl(4)]; blocks sharing a k-chunk land on one XCD's L2.
__global__ __launch_bounds__(512) void k_gemm1(const float* __restrict__ s,
                                               const ushort_t* __restrict__ Atab, const ushort_t* __restrict__ Btab,
                                               const float* __restrict__ bpkey,
                                               const ushort_t* __restrict__ Bm,
                                               float* __restrict__ partial) {
    __shared__ ushort_t As[128 * 72];
    __shared__ ushort_t Bs[128 * 72];
    __shared__ float sv_s[2048];
    __shared__ ushort_t r_s[2048];
    __shared__ float bp_s[256];
    int tid = threadIdx.x;
    int lane = tid & 63, wid = tid >> 6;
    int wr = wid >> 2, wc = wid & 3;           // 2 x 4 waves; wave tile 64m x 32n
    int bid = blockIdx.x;
    int xcd = bid & 7, j = bid >> 3;           // j: 0..31
    int nt = j & 1, mt = (j >> 1) & 3, kcl = j >> 3;   // kcl 0..3
    int kc = xcd * 4 + kcl;                    // 0..31
    int m0 = mt * 128, n0 = nt * 128;
    size_t k0 = (size_t)kc * 2048;
    if (tid < 256) bp_s[tid] = bpkey[tid];
    __syncthreads();
    {   // stage s-slice (128 rows x 16 k): 512 thr x float4 = exactly 2048 vals
        int row = tid >> 2, j4 = (tid & 3) * 4;
        float4 sv4 = *(const float4*)(s + (size_t)(m0 + row) * 512 + kc * 16 + j4);
        float svv[4] = {sv4.x, sv4.y, sv4.z, sv4.w};
        ushort_t rr[4];
        for (int q = 0; q < 4; ++q) {
            float sv = svv[q];
            int lo = 0, hi = 256;
            while (lo < hi) { int mid = (lo + hi) >> 1; if (bp_s[mid] <= sv) lo = mid + 1; else hi = mid; }
            rr[q] = (ushort_t)lo;
        }
        *(float4*)&sv_s[row * 16 + j4] = sv4;
        r_s[row * 16 + j4 + 0] = rr[0];
        r_s[row * 16 + j4 + 1] = rr[1];
        r_s[row * 16 + j4 + 2] = rr[2];
        r_s[row * 16 + j4 + 3] = rr[3];
    }
    __syncthreads();

    f32x4 acc[4][2] = {};
    short8 ta[2], tb[2], aval[2];
    uint4 vb[2];
    float svr[2];
    auto issue = [&](int kt) {
        int kl = kt >> 1;
        for (int i = 0; i < 2; ++i) {
            int q = tid + i * 512;
            int row = q >> 3, kcc = (q & 7) << 3;
            int e0 = ((kt & 1) << 6) + kcc;
            float sv = sv_s[row * 16 + kl];
            int r = r_s[row * 16 + kl];
            svr[i] = sv;
            ta[i] = *(const short8*)(Atab + r * 128 + e0);
            tb[i] = *(const short8*)(Btab + r * 128 + e0);
            vb[i] = *(const uint4*)(Bm + (size_t)(n0 + row) * 65536 + k0 + kt * 64 + kcc);
        }
    };
    auto cook = [&]() {
        for (int i = 0; i < 2; ++i) {
            float sv = svr[i];
            short8 o;
            for (int jj = 0; jj < 8; ++jj) {
                float y = fmaf(sv, bf2f((ushort_t)ta[i][jj]), bf2f((ushort_t)tb[i][jj]));
                y = y - fminf(fmaxf(y, -LAMBDA_), LAMBDA_);
                o[jj] = (short)f2bf(y);
            }
            aval[i] = o;
        }
    };
    issue(0);
    cook();
    for (int kt = 0; kt < 32; ++kt) {
        if (kt > 0) __syncthreads();
        for (int i = 0; i < 2; ++i) {
            int q = tid + i * 512;
            int row = q >> 3, kcc = (q & 7) << 3;
            *(short8*)&As[row * 72 + kcc] = aval[i];
            *(uint4*)&Bs[row * 72 + kcc] = vb[i];
        }
        __syncthreads();
        if (kt + 1 < 32) issue(kt + 1);
        for (int ks = 0; ks < 2; ++ks) {
            short8 a[4], b[2];
            int kk = ks * 32 + (lane >> 4) * 8;
            for (int mi = 0; mi < 4; ++mi)
                a[mi] = *(const short8*)&As[(wr * 64 + mi * 16 + (lane & 15)) * 72 + kk];
            for (int ni = 0; ni < 2; ++ni)
                b[ni] = *(const short8*)&Bs[(wc * 32 + ni * 16 + (lane & 15)) * 72 + kk];
            for (int mi = 0; mi < 4; ++mi)
                for (int ni = 0; ni < 2; ++ni)
                    acc[mi][ni] = __builtin_amdgcn_mfma_f32_16x16x32_bf16(a[mi], b[ni], acc[mi][ni], 0, 0, 0);
        }
        if (kt + 1 < 32) cook();
    }
    int mb0 = m0 + wr * 64 + ((lane >> 4) << 2);
    int nb0 = n0 + wc * 32 + (lane & 15);
    float* pbase = partial + (size_t)kc * 131072;
    for (int mi = 0; mi < 4; ++mi)
        for (int ni = 0; ni < 2; ++ni) {
            int mbase = mb0 + mi * 16;
            int n = nb0 + ni * 16;
            for (int r = 0; r < 4; ++r)
                pbase[(size_t)(mbase + r) * 256 + n] = acc[mi][ni][r];
        }
}

// ---------------- K10: final: a = leaky(sum_kc partial + h2b + fb1); out = a@fw2+fb2 ----------------
__global__ __launch_bounds__(128) void k_final(const float* __restrict__ partial, const float* __restrict__ h2b,
                                               const float* __restrict__ fb1,
                                               const float* __restrict__ fw2, const float* __restrict__ fb2,
                                               float* __restrict__ out) {
    __shared__ float a_s[256];
    int bn = blockIdx.x;
    int tid = threadIdx.x;
    for (int i = tid; i < 256; i += 128) {
        float acc = h2b[(size_t)bn * 256 + i] + fb1[i];
#pragma unroll 8
        for (int kc = 0; kc < 32; ++kc)
            acc += partial[((size_t)kc * 512 + bn) * 256 + i];
        a_s[i] = leaky_(acc);
    }
    __syncthreads();
    if (tid < 96) {
        float acc = fb2[tid];
        for (int hh = 0; hh < 256; ++hh)
            acc += a_s[hh] * fw2[hh * 96 + tid];
        int b = bn >> 6, n = bn & 63;
        out[(size_t)(b * 96 + tid) * 64 + n] = acc;
    }
}

extern "C" void kernel_launch(void* const* d_in, const int* in_sizes, int n_in,
                              void* d_out, int out_size, void* d_ws, size_t ws_size,
                              hipStream_t stream) {
    const float* x   = (const float*)d_in[0];
    const float* emb = (const float*)d_in[1];
    const float* w1  = (const float*)d_in[2];
    const float* b1  = (const float*)d_in[3];
    const float* w2  = (const float*)d_in[4];
    const float* b2  = (const float*)d_in[5];
    const float* tw1 = (const float*)d_in[6];
    const float* tb1 = (const float*)d_in[7];
    const float* tw2 = (const float*)d_in[8];
    const float* tb2 = (const float*)d_in[9];
    const float* fw1 = (const float*)d_in[10];
    const float* fb1 = (const float*)d_in[11];
    const float* fw2 = (const float*)d_in[12];
    const float* fb2 = (const float*)d_in[13];
    float* out = (float*)d_out;

    char* W = (char*)d_ws;
    size_t off = 0;
    auto take = [&](size_t bytes) { size_t r = off; off += (bytes + 255) & ~(size_t)255; return r; };
    ushort_t* fw1T  = (ushort_t*)(W + take(33554432));       // [32768 j''=h*128+e][512 t] bf16
    ushort_t* M2T   = (ushort_t*)(W + take(33554432));       // [256 h][65536 k'] bf16
    float* partial  = (float*)(W + take(32 * 512 * 256 * 4)); // [32 kc][512 bn][256 h] f32
    ushort_t* A1cat = (ushort_t*)(W + take(512 * 1536 * 2));
    ushort_t* B1cat = (ushort_t*)(W + take(1024 * 1536 * 2));
    ushort_t* Wt    = (ushort_t*)(W + take(512 * 512 * 2));
    ushort_t* tw2bf = (ushort_t*)(W + take(256 * 512 * 2));
    float* F1T      = (float*)(W + take(2 * 256 * 512 * 4)); // [2][h][t]
    ushort_t* F1sbf = (ushort_t*)(W + take(256 * 512 * 2));
    float* sbuf     = (float*)(W + take(512 * 512 * 4));
    ushort_t* hlbuf = (ushort_t*)(W + take(512 * 256 * 2));
    float* h2c      = (float*)(W + take(512 * 256 * 4));
    ushort_t* P2T   = (ushort_t*)(W + take(256 * 256 * 2));
    float* p2v      = (float*)(W + take(256 * 4));
    ushort_t* Atab  = (ushort_t*)(W + take(257 * 128 * 2));
    ushort_t* Btab  = (ushort_t*)(W + take(257 * 128 * 2));
    float* bpkey    = (float*)(W + take(256 * 4));
    float* h2b      = (float*)(W + take(512 * 256 * 4));
    (void)ws_size; (void)in_sizes; (void)n_in; (void)out_size;

    k_setup<<<3072, 256, 0, stream>>>(tw2, B1cat, Wt, tw2bf);
    k_pack_tw1<<<32, 256, 0, stream>>>(tw1, B1cat);
    k_transpose_x<<<256, 256, 0, stream>>>(x, A1cat);
    k_prep<<<1, 256, 0, stream>>>(emb, w1, b1, w2, b2, Atab, Btab, bpkey);
    k_transpose_fw1<<<4096, 256, 0, stream>>>(fw1, fw1T);
    k_reduce_F2<<<256, 256, 0, stream>>>(fw1T, emb, F1T);
    k_pack_F<<<256, 64, 0, stream>>>(F1T, F1T + 131072, tb2, B1cat, F1sbf, p2v);
    // G1: [s | hl | h2c] = xTcat @ B1cat^T   (M=512, N=1024, K=1536 hi/lo)
    k_mfma<2><<<32, 256, 0, stream>>>(A1cat, B1cat, 1536, 1536, 24, 8, sbuf, hlbuf, h2c, tb1);
    // GEMM0: M2T = Wt @ fw1T^T  (M=512 k, N=32768 j'', K=512 t)
    k_mfma<0><<<1024, 256, 0, stream>>>(Wt, fw1T, 512, 512, 8, 256, M2T, nullptr, nullptr, nullptr);
    // P2' = tw2 @ F1s  (M=256 h'', N=256 h', K=512 t) -> P2T
    k_mfma<4><<<4, 256, 0, stream>>>(tw2bf, F1sbf, 512, 512, 8, 2, P2T, nullptr, nullptr, nullptr);
    // GEMM1 (fused softshrink-A): partial[kc] = cook(s) @ M2T^T  (split-K 32)
    k_gemm1<<<256, 512, 0, stream>>>(sbuf, Atab, Btab, bpkey, M2T, partial);
    // h2b = hl @ P2'^T + p2v + h2c  (M=512, N=256, K=256)
    k_mfma<5><<<8, 256, 0, stream>>>(hlbuf, P2T, 256, 256, 4, 2, h2b, h2c, nullptr, p2v);
    k_final<<<512, 128, 0, stream>>>(partial, h2b, fb1, fw2, fb2, out);
}

// Round 9
// 209.812 us; speedup vs baseline: 1.5736x; 1.1633x over previous
//
#include <hip/hip_runtime.h>
#include <hip/hip_bf16.h>

// B=8, T=512, N=64, E=128, H=256, P=96.  bn = b*64+n (512 rows).
// Identities:
//  xe = x_noD*emb  => rfft factorizes: spectral scalar s[bn,k] (packed: k<=256 real, k>256 imag)
//  mlp(s*emb) piecewise-linear in s (257 regions; tables Atab/Btab[r][e])
//  xt-part of flat@fw1:  h2[bn,h] = sum_{k,e} Yp[bn,k,e] * M2[k,e,h],
//      M2[k,(h,e)] = sum_t W[t,k] fw1[(t*128+e)*256+h]   (W = packed irfft basis)
//      Yp values are generated IN-REGISTER inside GEMM1 (fused softshrink), never materialized.
//  xn-part:   xn@F1s = hl@(tw2@F1s) + tb2@F1s,  F1s[t,h] = sum_e fw1
//  bias-part: x_noD@F1e,                        F1e[t,h] = sum_e (1+emb_e) fw1
//  s and x@F1e computed via hi/lo bf16 K-concat MFMA (A=[hi|lo|hi], B=[hi;hi;lo]).
// GEMM0/GEMM1 use global_load_lds (width 16) + source-pre-swizzled LDS (slot^(row&7)),
// double-buffered, ONE barrier per K-step (m97 schedule), setprio around MFMA.

typedef unsigned int uint;
typedef unsigned short ushort_t;
typedef __attribute__((ext_vector_type(4))) float f32x4;
typedef __attribute__((ext_vector_type(8))) short short8;

#define LAMBDA_ 0.001f
#define RSQRT512 0.044194173824159220f

__device__ __forceinline__ ushort_t f2bf(float f) {
    uint u = __float_as_uint(f);
    uint r = (u + 0x7FFFu + ((u >> 16) & 1u)) >> 16;
    return (ushort_t)r;
}
__device__ __forceinline__ float bf2f(ushort_t v) { return __uint_as_float(((uint)v) << 16); }
__device__ __forceinline__ float leaky_(float v) { return v >= 0.f ? v : 0.01f * v; }

__device__ __forceinline__ void gload_lds16(const ushort_t* g, ushort_t* l) {
    __builtin_amdgcn_global_load_lds((const __attribute__((address_space(1))) void*)g,
                                     (__attribute__((address_space(3))) void*)l, 16, 0, 0);
}

// ---------------- K0: transpose x [8][512][64] -> A1cat [512 bn][1536] (hi|lo|hi) ----------------
__global__ __launch_bounds__(256) void k_transpose_x(const float* __restrict__ x, ushort_t* __restrict__ A1cat) {
    __shared__ float tile[32][33];
    int bid = blockIdx.x;             // 8 * 16 * 2 = 256
    int b = bid >> 5;
    int rem = bid & 31;
    int t0 = (rem >> 1) << 5;
    int n0 = (rem & 1) << 5;
    int tx = threadIdx.x & 31, ty = threadIdx.x >> 5;
    for (int i = 0; i < 4; ++i) {
        int tt = ty * 4 + i;
        tile[tt][tx] = x[(size_t)(b * 512 + t0 + tt) * 64 + n0 + tx];
    }
    __syncthreads();
    for (int i = 0; i < 4; ++i) {
        int nn = ty * 4 + i;
        float v = tile[tx][nn];
        ushort_t hi = f2bf(v);
        ushort_t lo = f2bf(v - bf2f(hi));
        size_t row = (size_t)(b * 64 + n0 + nn) * 1536;
        int t = t0 + tx;
        A1cat[row + t] = hi;
        A1cat[row + 512 + t] = lo;
        A1cat[row + 1024 + t] = hi;
    }
}

// ---------------- K1: setup — B1cat DFT rows, Wt, tw2_bf ----------------
__global__ __launch_bounds__(256) void k_setup(const float* __restrict__ tw2,
                                               ushort_t* __restrict__ B1cat, ushort_t* __restrict__ Wt,
                                               ushort_t* __restrict__ tw2_bf) {
    int bid = blockIdx.x;
    int region = bid >> 10;
    int id = ((bid & 1023) << 8) + threadIdx.x;
    int a = id >> 9, c = id & 511;
    if (region == 0) {       // B1cat rows 0-511: D[t=c][k=a]
        int f = (a <= 256) ? a : (a - 256);
        int m = (c * f) & 511;
        float ang = (float)m * (6.283185307179586f / 512.0f);
        float v = ((a <= 256) ? cosf(ang) : -sinf(ang)) * RSQRT512;
        ushort_t hi = f2bf(v);
        ushort_t lo = f2bf(v - bf2f(hi));
        size_t row = (size_t)a * 1536;
        B1cat[row + c] = hi;
        B1cat[row + 512 + c] = hi;
        B1cat[row + 1024 + c] = lo;
    } else if (region == 1) {  // Wt[k=a][t=c]
        int f = (a <= 256) ? a : (a - 256);
        int m = (c * f) & 511;
        float ang = (float)m * (6.283185307179586f / 512.0f);
        float v = ((a <= 256) ? cosf(ang) : -sinf(ang)) * RSQRT512;
        float sc = (a == 0 || a == 256) ? 1.0f : 2.0f;
        Wt[id] = f2bf(v * sc);
    } else {                   // tw2_bf: 512 blocks used
        if ((bid & 1023) < 512) tw2_bf[id] = f2bf(tw2[id]);
    }
}

// ---------------- K2: pack tw1 -> B1cat rows 512-767 (transposed, hi|hi|lo) ----------------
__global__ __launch_bounds__(256) void k_pack_tw1(const float* __restrict__ tw1, ushort_t* __restrict__ B1cat) {
    __shared__ float tile[64][65];
    int bid = blockIdx.x;            // 8 t-tiles * 4 h-tiles = 32
    int t0 = (bid & 7) << 6, h0 = (bid >> 3) << 6;
    int tid = threadIdx.x;
    for (int i = 0; i < 16; ++i) {
        int idx = tid + i * 256;
        int r = idx >> 6, cc = idx & 63;
        tile[r][cc] = tw1[(size_t)(t0 + r) * 256 + h0 + cc];
    }
    __syncthreads();
    for (int i = 0; i < 16; ++i) {
        int idx = tid + i * 256;
        int rr = idx >> 6, cc2 = idx & 63;      // rr: h, cc2: t
        float v = tile[cc2][rr];
        ushort_t hi = f2bf(v);
        ushort_t lo = f2bf(v - bf2f(hi));
        size_t row = (size_t)(512 + h0 + rr) * 1536;
        int t = t0 + cc2;
        B1cat[row + t] = hi;
        B1cat[row + 512 + t] = hi;
        B1cat[row + 1024 + t] = lo;
    }
}

// ---------------- K3: piecewise-linear tables (1 block); w2 staged in LDS ----------------
__global__ __launch_bounds__(256) void k_prep(const float* __restrict__ emb, const float* __restrict__ w1,
                                              const float* __restrict__ b1, const float* __restrict__ w2,
                                              const float* __restrict__ b2,
                                              ushort_t* __restrict__ Atab, ushort_t* __restrict__ Btab,
                                              float* __restrict__ bpkey_g) {
    __shared__ float w2s[256 * 128];   // 128 KB
    __shared__ float u_s[256], b1_s[256], key_s[256];
    __shared__ int idx_s[256];
    int tid = threadIdx.x;
    for (int i = 0; i < 32; ++i) {
        int idx4 = tid + i * 256;
        *(float4*)&w2s[idx4 * 4] = *(const float4*)&w2[idx4 * 4];
    }
    float acc = 0.f;
    for (int e = 0; e < 128; ++e) acc += emb[e] * w1[e * 256 + tid];
    u_s[tid] = acc;
    float bb0 = b1[tid];
    b1_s[tid] = bb0;
    key_s[tid] = (acc == 0.f) ? INFINITY : (-bb0 / acc);
    idx_s[tid] = tid;
    __syncthreads();
    for (int k = 2; k <= 256; k <<= 1) {
        for (int j = k >> 1; j > 0; j >>= 1) {
            int ixj = tid ^ j;
            if (ixj > tid) {
                bool up = ((tid & k) == 0);
                float a0 = key_s[tid], a1 = key_s[ixj];
                if ((a0 > a1) == up) {
                    key_s[tid] = a1; key_s[ixj] = a0;
                    int t0 = idx_s[tid]; idx_s[tid] = idx_s[ixj]; idx_s[ixj] = t0;
                }
            }
            __syncthreads();
        }
    }
    bpkey_g[tid] = key_s[tid];
    if (tid < 128) {
        int e = tid;
        float aA = 0.f, aB = 0.f;
        for (int h = 0; h < 256; ++h) {
            float uu = u_s[h], bbh = b1_s[h];
            float c = (uu < 0.f || (uu == 0.f && bbh >= 0.f)) ? 1.0f : 0.01f;
            float w = w2s[h * 128 + e];
            aA += c * uu * w;
            aB += c * bbh * w;
        }
        aB += b2[e];
        Atab[e] = f2bf(aA);
        Btab[e] = f2bf(aB);
        for (int r = 1; r <= 256; ++r) {
            int h = idx_s[r - 1];
            float uu = u_s[h], bbh = b1_s[h];
            float w = w2s[h * 128 + e];
            float sgn = (uu > 0.f) ? 0.99f : -0.99f;
            aA += sgn * uu * w;
            aB += sgn * bbh * w;
            Atab[r * 128 + e] = f2bf(aA);
            Btab[r * 128 + e] = f2bf(aB);
        }
    }
}

// ---------------- K4: transpose fw1 [(t,e)][h] f32 -> fw1T[(h*128+e)][t] bf16 ----------------
__global__ __launch_bounds__(256) void k_transpose_fw1(const float* __restrict__ fw1, ushort_t* __restrict__ fw1T) {
    __shared__ float tile[64][65];
    int bid = blockIdx.x;
    int e  = bid & 127;
    int hb = (bid >> 7) & 3;
    int tt = bid >> 9;
    int t0 = tt << 6, h0 = hb << 6;
    int tid = threadIdx.x;
    for (int i = 0; i < 4; ++i) {
        int idx = tid + i * 256;            // 0..1023 float4s
        int r = idx >> 4, c4 = idx & 15;
        const float* src = fw1 + ((size_t)(t0 + r) * 128 + e) * 256 + h0 + c4 * 4;
        float4 v = *(const float4*)src;
        tile[r][c4 * 4 + 0] = v.x;
        tile[r][c4 * 4 + 1] = v.y;
        tile[r][c4 * 4 + 2] = v.z;
        tile[r][c4 * 4 + 3] = v.w;
    }
    __syncthreads();
    for (int p = 0; p < 2; ++p) {
        int idx = tid + p * 256;            // 0..511 short8s
        int hh = idx >> 3, tg = idx & 7;
        short8 o;
        for (int j = 0; j < 8; ++j) o[j] = (short)f2bf(tile[tg * 8 + j][hh]);
        *(short8*)(fw1T + ((size_t)(h0 + hh) * 128 + e) * 512 + t0 + tg * 8) = o;
    }
}

// ---------------- K4b: F1 from fw1T: F1T[0][h][t]=sum_e fw1T, F1T[1][h][t]=sum_e(1+emb)fw1T ----------------
__global__ __launch_bounds__(256) void k_reduce_F2(const ushort_t* __restrict__ fw1T, const float* __restrict__ emb,
                                                   float* __restrict__ F1T) {
    __shared__ float embs[128];
    int h = blockIdx.x;                  // 256
    int tid = threadIdx.x;
    if (tid < 128) embs[tid] = 1.f + emb[tid];
    __syncthreads();
    int t2 = tid * 2;
    const ushort_t* base = fw1T + ((size_t)h << 16) + t2;
    float as0 = 0.f, as1 = 0.f, ae0 = 0.f, ae1 = 0.f;
#pragma unroll 4
    for (int e = 0; e < 128; ++e) {
        uint v = *(const uint*)(base + (size_t)e * 512);
        float v0 = bf2f((ushort_t)(v & 0xffff));
        float v1 = bf2f((ushort_t)(v >> 16));
        float w = embs[e];
        as0 += v0; as1 += v1;
        ae0 += w * v0; ae1 += w * v1;
    }
    F1T[(size_t)h * 512 + t2] = as0;
    F1T[(size_t)h * 512 + t2 + 1] = as1;
    F1T[131072 + (size_t)h * 512 + t2] = ae0;
    F1T[131072 + (size_t)h * 512 + t2 + 1] = ae1;
}

// ---------------- K5: pack F1s/F1e: B1cat rows 768-1023 (F1e hi|hi|lo), F1sT_bf, p2v = tb2@F1s ----------------
__global__ __launch_bounds__(64) void k_pack_F(const float* __restrict__ F1sT, const float* __restrict__ F1eT,
                                               const float* __restrict__ tb2,
                                               ushort_t* __restrict__ B1cat, ushort_t* __restrict__ F1sT_bf,
                                               float* __restrict__ p2v) {
    int h = blockIdx.x;                   // 256
    int lane = threadIdx.x;
    int t = lane * 8;
    float p2 = 0.f;
    short8 shi, ehi, elo;
    for (int j = 0; j < 8; ++j) {
        float vs = F1sT[(size_t)h * 512 + t + j];
        float ve = F1eT[(size_t)h * 512 + t + j];
        p2 += tb2[t + j] * vs;
        shi[j] = (short)f2bf(vs);
        ushort_t hi = f2bf(ve);
        ehi[j] = (short)hi;
        elo[j] = (short)f2bf(ve - bf2f(hi));
    }
    *(short8*)(F1sT_bf + (size_t)h * 512 + t) = shi;
    size_t row = (size_t)(768 + h) * 1536;
    *(short8*)(B1cat + row + t) = ehi;
    *(short8*)(B1cat + row + 512 + t) = ehi;
    *(short8*)(B1cat + row + 1024 + t) = elo;
    for (int o = 32; o > 0; o >>= 1) p2 += __shfl_xor(p2, o);
    if (lane == 0) p2v[h] = p2;
}

// ---------------- generic 128x128-tile bf16 MFMA GEMM (small ones); A [M][K] lda, B [N][K] ldb ----------------
// EPI 2: G1: s f32 / hl bf16(leaky+tb1) / h2c f32 split by n  (grid 32)
// EPI 4: P2T transposed bf16 store (grid 4)
// EPI 5: h2b = acc + p2v[n] + h2c (grid 8)
template<int EPI>
__global__ __launch_bounds__(256) void k_mfma(const ushort_t* __restrict__ A, const ushort_t* __restrict__ Bm,
                                              int lda, int ldb, int kIters, int nTiles,
                                              void* __restrict__ C0, void* __restrict__ C1,
                                              void* __restrict__ C2, const float* __restrict__ aux) {
    __shared__ ushort_t shmem[2 * 128 * 72];
    ushort_t* As = shmem;
    ushort_t* Bs = shmem + 128 * 72;
    int tid = threadIdx.x;
    int lane = tid & 63, wid = tid >> 6;
    int wr = wid >> 1, wc = wid & 1;
    int bid = blockIdx.x;
    int nt = bid % nTiles, mt = bid / nTiles;
    int m0 = mt * 128, n0 = nt * 128;
    f32x4 acc[4][4] = {};
    for (int kt = 0; kt < kIters; ++kt) {
        int kb = kt * 64;
        __syncthreads();
        {
            uint4 va[4], vb[4];
            for (int i = 0; i < 4; ++i) {
                int q = tid + i * 256;
                int row = q >> 3, kcc = (q & 7) << 3;
                va[i] = *(const uint4*)(A + (size_t)(m0 + row) * lda + kb + kcc);
                vb[i] = *(const uint4*)(Bm + (size_t)(n0 + row) * ldb + kb + kcc);
            }
            for (int i = 0; i < 4; ++i) {
                int q = tid + i * 256;
                int row = q >> 3, kcc = (q & 7) << 3;
                *(uint4*)&As[row * 72 + kcc] = va[i];
                *(uint4*)&Bs[row * 72 + kcc] = vb[i];
            }
        }
        __syncthreads();
        for (int ks = 0; ks < 2; ++ks) {
            short8 a[4], b[4];
            int kk = ks * 32 + (lane >> 4) * 8;
            for (int mi = 0; mi < 4; ++mi)
                a[mi] = *(const short8*)&As[(wr * 64 + mi * 16 + (lane & 15)) * 72 + kk];
            for (int ni = 0; ni < 4; ++ni)
                b[ni] = *(const short8*)&Bs[(wc * 64 + ni * 16 + (lane & 15)) * 72 + kk];
            for (int mi = 0; mi < 4; ++mi)
                for (int ni = 0; ni < 4; ++ni)
                    acc[mi][ni] = __builtin_amdgcn_mfma_f32_16x16x32_bf16(a[mi], b[ni], acc[mi][ni], 0, 0, 0);
        }
    }
    int mb0 = m0 + wr * 64 + ((lane >> 4) << 2);
    int nb0 = n0 + wc * 64 + (lane & 15);
    for (int mi = 0; mi < 4; ++mi) {
        for (int ni = 0; ni < 4; ++ni) {
            int mbase = mb0 + mi * 16;
            int n = nb0 + ni * 16;
            if (EPI == 2) {
                float* s = (float*)C0;
                ushort_t* hl = (ushort_t*)C1;
                float* h2c = (float*)C2;
                for (int r = 0; r < 4; ++r) {
                    int m = mbase + r;
                    float v = acc[mi][ni][r];
                    if (n < 512) s[(size_t)m * 512 + n] = v;
                    else if (n < 768) hl[(size_t)m * 256 + (n - 512)] = f2bf(leaky_(v + aux[n - 512]));
                    else h2c[(size_t)m * 256 + (n - 768)] = v;
                }
            } else if (EPI == 4) {
                ushort_t* P2T = (ushort_t*)C0;
                ushort4 o;
                o.x = f2bf(acc[mi][ni][0]);
                o.y = f2bf(acc[mi][ni][1]);
                o.z = f2bf(acc[mi][ni][2]);
                o.w = f2bf(acc[mi][ni][3]);
                *(ushort4*)(P2T + (size_t)n * 256 + mbase) = o;
            } else if (EPI == 5) {
                float* h2b = (float*)C0;
                const float* h2c = (const float*)C1;
                for (int r = 0; r < 4; ++r) {
                    int m = mbase + r;
                    h2b[(size_t)m * 256 + n] = acc[mi][ni][r] + aux[n] + h2c[(size_t)m * 256 + n];
                }
            }
        }
    }
}

// ---------------- GEMM0: M2T = Wt @ fw1T^T (M=512, N=32768, K=512) ----------------
// 512 thr (8 waves 2x4), BM=128, BN=128, BK=64, dbuf LDS via global_load_lds (swizzled source),
// ONE barrier per K-step. grid 1024 = xcd(8) x [mt(4) x ntl(32)].
__global__ __launch_bounds__(512) void k_gemm0(const ushort_t* __restrict__ A, const ushort_t* __restrict__ Bm,
                                               ushort_t* __restrict__ M2T) {
    __shared__ ushort_t As[2][128 * 64];
    __shared__ ushort_t Bs[2][128 * 64];
    int tid = threadIdx.x;
    int lane = tid & 63, wid = tid >> 6;
    int wr = wid >> 2, wc = wid & 3;          // 2 x 4 waves; wave tile 64m x 32n
    int bid = blockIdx.x;
    int xx = bid & 7, y = bid >> 3;
    int mt = y & 3;
    int nt = ((y >> 2) << 3) | xx;
    int m0 = mt * 128, n0 = nt * 128;
    int lrow = lane >> 3;                     // 0..7
    int sg = (lane & 7) ^ lrow;               // swizzled source 16B-slot
    auto issue = [&](int kt, int buf) {
        int kb = kt * 64;
        for (int i = 0; i < 2; ++i) {
            int rbase = wid * 16 + i * 8;
            gload_lds16(A + (size_t)(m0 + rbase + lrow) * 512 + kb + sg * 8, &As[buf][wid * 1024 + i * 512]);
            gload_lds16(Bm + (size_t)(n0 + rbase + lrow) * 512 + kb + sg * 8, &Bs[buf][wid * 1024 + i * 512]);
        }
    };
    f32x4 acc[4][2] = {};
    issue(0, 0);
    __syncthreads();
    int cur = 0;
    for (int kt = 0; kt < 8; ++kt) {
        int nxt = cur ^ 1;
        if (kt + 1 < 8) issue(kt + 1, nxt);
        __builtin_amdgcn_s_setprio(1);
        for (int ks = 0; ks < 2; ++ks) {
            short8 a[4], b[2];
            int sl = ks * 4 + (lane >> 4);
            for (int mi = 0; mi < 4; ++mi) {
                int row = wr * 64 + mi * 16 + (lane & 15);
                a[mi] = *(const short8*)&As[cur][row * 64 + ((sl ^ (row & 7)) << 3)];
            }
            for (int ni = 0; ni < 2; ++ni) {
                int row = wc * 32 + ni * 16 + (lane & 15);
                b[ni] = *(const short8*)&Bs[cur][row * 64 + ((sl ^ (row & 7)) << 3)];
            }
            for (int mi = 0; mi < 4; ++mi)
                for (int ni = 0; ni < 2; ++ni)
                    acc[mi][ni] = __builtin_amdgcn_mfma_f32_16x16x32_bf16(a[mi], b[ni], acc[mi][ni], 0, 0, 0);
        }
        __builtin_amdgcn_s_setprio(0);
        __syncthreads();
        cur = nxt;
    }
    // epilogue: stage 128x128 bf16 C tile across As[0..1] (exactly 32KB), swizzled, then linear copy
    ushort_t* cstage = &As[0][0];
    for (int mi = 0; mi < 4; ++mi) {
        int ml = wr * 64 + mi * 16 + ((lane >> 4) << 2);
        for (int ni = 0; ni < 2; ++ni) {
            int nl = wc * 32 + ni * 16 + (lane & 15);
            for (int r = 0; r < 4; ++r) {
                int row = ml + r;
                cstage[row * 128 + (nl ^ ((row & 7) << 4))] = f2bf(acc[mi][ni][r]);
            }
        }
    }
    __syncthreads();
    short8* d8 = (short8*)(M2T + ((size_t)(n0 >> 7) << 16) + (size_t)m0 * 128);
    for (int i = 0; i < 4; ++i) {
        int p = tid + i * 512;                 // short8 index 0..2047
        int row = p >> 4;
        int col0 = (p & 15) * 8;
        d8[p] = *(const short8*)&cstage[row * 128 + (col0 ^ ((row & 7) << 4))];
    }
}

// ---------------- GEMM1 (fused): partial[kc] = cook(s) @ M2T^T chunk ----------------
// M=512, N=256, K=65536. BM=128, BN=128, split-K 64 chunks of 1024 (8 k x 128 e).
// B via global_load_lds (swizzled source, dbuf); A cooked in-register -> swizzled ds_write.
// ONE barrier per K-step. grid 512 = xcd(8) x [kcl(8) x mt(4) x nt(2)].
__global__ __launch_bounds__(512) void k_gemm1(const float* __restrict__ s,
                                               const ushort_t* __restrict__ Atab, const ushort_t* __restrict__ Btab,
                                               const float* __restrict__ bpkey,
                                               const ushort_t* __restrict__ Bm,
                                               float* __restrict__ partial) {
    __shared__ ushort_t As[2][128 * 64];
    __shared__ ushort_t Bs[2][128 * 64];
    __shared__ float sv_s[1024];
    __shared__ ushort_t r_s[1024];
    __shared__ float bp_s[256];
    int tid = threadIdx.x;
    int lane = tid & 63, wid = tid >> 6;
    int wr = wid >> 2, wc = wid & 3;           // 2 x 4 waves; wave tile 64m x 32n
    int bid = blockIdx.x;
    int xcd = bid & 7, j = bid >> 3;           // j: 0..63
    int kcl = j & 7, mt = (j >> 3) & 3, nt = j >> 5;
    int kc = xcd * 8 + kcl;                    // 0..63
    int m0 = mt * 128, n0 = nt * 128;
    int k0 = kc * 1024;
    if (tid < 256) bp_s[tid] = bpkey[tid];
    __syncthreads();
    {   // stage s-slice (128 rows x 8 k) + region lookup: 512 thr x float2
        int row = tid >> 2, j2 = (tid & 3) * 2;
        float2 sv2 = *(const float2*)(s + (size_t)(m0 + row) * 512 + kc * 8 + j2);
        float svv[2] = {sv2.x, sv2.y};
        for (int q = 0; q < 2; ++q) {
            float sv = svv[q];
            int lo = 0, hi = 256;
            while (lo < hi) { int mid = (lo + hi) >> 1; if (bp_s[mid] <= sv) lo = mid + 1; else hi = mid; }
            sv_s[row * 8 + j2 + q] = sv;
            r_s[row * 8 + j2 + q] = (ushort_t)lo;
        }
    }
    __syncthreads();

    int lrow = lane >> 3;
    int sg = (lane & 7) ^ lrow;
    auto issueB = [&](int kt, int buf) {
        int kb = k0 + kt * 64;
        for (int i = 0; i < 2; ++i) {
            int rbase = wid * 16 + i * 8;
            gload_lds16(Bm + (size_t)(n0 + rbase + lrow) * 65536 + kb + sg * 8, &Bs[buf][wid * 1024 + i * 512]);
        }
    };
    short8 ta[2], tb[2];
    float svr[2];
    auto gather = [&](int kt) {
        int kl = kt >> 1;
        for (int i = 0; i < 2; ++i) {
            int q = tid + i * 512;
            int row = q >> 3, slot = q & 7;
            int e0 = ((kt & 1) << 6) + slot * 8;
            int r = r_s[row * 8 + kl];
            svr[i] = sv_s[row * 8 + kl];
            ta[i] = *(const short8*)(Atab + r * 128 + e0);
            tb[i] = *(const short8*)(Btab + r * 128 + e0);
        }
    };
    auto cookwrite = [&](int buf) {
        for (int i = 0; i < 2; ++i) {
            int q = tid + i * 512;
            int row = q >> 3, slot = q & 7;
            float sv = svr[i];
            short8 o;
            for (int jj = 0; jj < 8; ++jj) {
                float y = fmaf(sv, bf2f((ushort_t)ta[i][jj]), bf2f((ushort_t)tb[i][jj]));
                y = y - fminf(fmaxf(y, -LAMBDA_), LAMBDA_);
                o[jj] = (short)f2bf(y);
            }
            *(short8*)&As[buf][row * 64 + ((slot ^ (row & 7)) << 3)] = o;
        }
    };

    f32x4 acc[4][2] = {};
    issueB(0, 0);
    gather(0);
    cookwrite(0);
    __syncthreads();
    int cur = 0;
    for (int kt = 0; kt < 16; ++kt) {
        int nxt = cur ^ 1;
        if (kt + 1 < 16) { issueB(kt + 1, nxt); gather(kt + 1); }
        __builtin_amdgcn_s_setprio(1);
        for (int ks = 0; ks < 2; ++ks) {
            short8 a[4], b[2];
            int sl = ks * 4 + (lane >> 4);
            for (int mi = 0; mi < 4; ++mi) {
                int row = wr * 64 + mi * 16 + (lane & 15);
                a[mi] = *(const short8*)&As[cur][row * 64 + ((sl ^ (row & 7)) << 3)];
            }
            for (int ni = 0; ni < 2; ++ni) {
                int row = wc * 32 + ni * 16 + (lane & 15);
                b[ni] = *(const short8*)&Bs[cur][row * 64 + ((sl ^ (row & 7)) << 3)];
            }
            for (int mi = 0; mi < 4; ++mi)
                for (int ni = 0; ni < 2; ++ni)
                    acc[mi][ni] = __builtin_amdgcn_mfma_f32_16x16x32_bf16(a[mi], b[ni], acc[mi][ni], 0, 0, 0);
        }
        __builtin_amdgcn_s_setprio(0);
        if (kt + 1 < 16) cookwrite(nxt);
        __syncthreads();
        cur = nxt;
    }
    int mb0 = m0 + wr * 64 + ((lane >> 4) << 2);
    int nb0 = wc * 32 + (lane & 15);
    float* pbase = partial + (size_t)kc * 131072 + n0;
    for (int mi = 0; mi < 4; ++mi)
        for (int ni = 0; ni < 2; ++ni) {
            int mbase = mb0 + mi * 16;
            int n = nb0 + ni * 16;
            for (int r = 0; r < 4; ++r)
                pbase[(size_t)(mbase + r) * 256 + n] = acc[mi][ni][r];
        }
}

// ---------------- K10: final: a = leaky(sum_kc partial + h2b + fb1); out = a@fw2+fb2 ----------------
__global__ __launch_bounds__(128) void k_final(const float* __restrict__ partial, const float* __restrict__ h2b,
                                               const float* __restrict__ fb1,
                                               const float* __restrict__ fw2, const float* __restrict__ fb2,
                                               float* __restrict__ out) {
    __shared__ float a_s[256];
    int bn = blockIdx.x;
    int tid = threadIdx.x;
    for (int i = tid; i < 256; i += 128) {
        float acc = h2b[(size_t)bn * 256 + i] + fb1[i];
#pragma unroll 8
        for (int kc = 0; kc < 64; ++kc)
            acc += partial[((size_t)kc * 512 + bn) * 256 + i];
        a_s[i] = leaky_(acc);
    }
    __syncthreads();
    if (tid < 96) {
        float acc = fb2[tid];
        for (int hh = 0; hh < 256; ++hh)
            acc += a_s[hh] * fw2[hh * 96 + tid];
        int b = bn >> 6, n = bn & 63;
        out[(size_t)(b * 96 + tid) * 64 + n] = acc;
    }
}

extern "C" void kernel_launch(void* const* d_in, const int* in_sizes, int n_in,
                              void* d_out, int out_size, void* d_ws, size_t ws_size,
                              hipStream_t stream) {
    const float* x   = (const float*)d_in[0];
    const float* emb = (const float*)d_in[1];
    const float* w1  = (const float*)d_in[2];
    const float* b1  = (const float*)d_in[3];
    const float* w2  = (const float*)d_in[4];
    const float* b2  = (const float*)d_in[5];
    const float* tw1 = (const float*)d_in[6];
    const float* tb1 = (const float*)d_in[7];
    const float* tw2 = (const float*)d_in[8];
    const float* tb2 = (const float*)d_in[9];
    const float* fw1 = (const float*)d_in[10];
    const float* fb1 = (const float*)d_in[11];
    const float* fw2 = (const float*)d_in[12];
    const float* fb2 = (const float*)d_in[13];
    float* out = (float*)d_out;

    char* W = (char*)d_ws;
    size_t off = 0;
    auto take = [&](size_t bytes) { size_t r = off; off += (bytes + 255) & ~(size_t)255; return r; };
    ushort_t* fw1T  = (ushort_t*)(W + take(33554432));       // [32768 j''=h*128+e][512 t] bf16
    ushort_t* M2T   = (ushort_t*)(W + take(33554432));       // [256 h][65536 k'] bf16
    float* partial  = (float*)(W + take(64 * 512 * 256 * 4)); // [64 kc][512 bn][256 h] f32
    ushort_t* A1cat = (ushort_t*)(W + take(512 * 1536 * 2));
    ushort_t* B1cat = (ushort_t*)(W + take(1024 * 1536 * 2));
    ushort_t* Wt    = (ushort_t*)(W + take(512 * 512 * 2));
    ushort_t* tw2bf = (ushort_t*)(W + take(256 * 512 * 2));
    float* F1T      = (float*)(W + take(2 * 256 * 512 * 4)); // [2][h][t]
    ushort_t* F1sbf = (ushort_t*)(W + take(256 * 512 * 2));
    float* sbuf     = (float*)(W + take(512 * 512 * 4));
    ushort_t* hlbuf = (ushort_t*)(W + take(512 * 256 * 2));
    float* h2c      = (float*)(W + take(512 * 256 * 4));
    ushort_t* P2T   = (ushort_t*)(W + take(256 * 256 * 2));
    float* p2v      = (float*)(W + take(256 * 4));
    ushort_t* Atab  = (ushort_t*)(W + take(257 * 128 * 2));
    ushort_t* Btab  = (ushort_t*)(W + take(257 * 128 * 2));
    float* bpkey    = (float*)(W + take(256 * 4));
    float* h2b      = (float*)(W + take(512 * 256 * 4));
    (void)ws_size; (void)in_sizes; (void)n_in; (void)out_size;

    k_setup<<<3072, 256, 0, stream>>>(tw2, B1cat, Wt, tw2bf);
    k_pack_tw1<<<32, 256, 0, stream>>>(tw1, B1cat);
    k_transpose_x<<<256, 256, 0, stream>>>(x, A1cat);
    k_prep<<<1, 256, 0, stream>>>(emb, w1, b1, w2, b2, Atab, Btab, bpkey);
    k_transpose_fw1<<<4096, 256, 0, stream>>>(fw1, fw1T);
    k_reduce_F2<<<256, 256, 0, stream>>>(fw1T, emb, F1T);
    k_pack_F<<<256, 64, 0, stream>>>(F1T, F1T + 131072, tb2, B1cat, F1sbf, p2v);
    // G1: [s | hl | h2c] = xTcat @ B1cat^T   (M=512, N=1024, K=1536 hi/lo)
    k_mfma<2><<<32, 256, 0, stream>>>(A1cat, B1cat, 1536, 1536, 24, 8, sbuf, hlbuf, h2c, tb1);
    // GEMM0: M2T = Wt @ fw1T^T  (M=512 k, N=32768 j'', K=512 t)
    k_gemm0<<<1024, 512, 0, stream>>>(Wt, fw1T, M2T);
    // P2' = tw2 @ F1s  (M=256 h'', N=256 h', K=512 t) -> P2T
    k_mfma<4><<<4, 256, 0, stream>>>(tw2bf, F1sbf, 512, 512, 8, 2, P2T, nullptr, nullptr, nullptr);
    // GEMM1 (fused softshrink-A): partial[kc] = cook(s) @ M2T^T  (split-K 64)
    k_gemm1<<<512, 512, 0, stream>>>(sbuf, Atab, Btab, bpkey, M2T, partial);
    // h2b = hl @ P2'^T + p2v + h2c  (M=512, N=256, K=256)
    k_mfma<5><<<8, 256, 0, stream>>>(hlbuf, P2T, 256, 256, 4, 2, h2b, h2c, nullptr, p2v);
    k_final<<<512, 128, 0, stream>>>(partial, h2b, fb1, fw2, fb2, out);
}

// Round 10
// 184.477 us; speedup vs baseline: 1.7897x; 1.1373x over previous
//
#include <hip/hip_runtime.h>
#include <hip/hip_bf16.h>

// B=8, T=512, N=64, E=128, H=256, P=96.  bn = b*64+n (512 rows).
// Identities:
//  xe = x_noD*emb  => rfft factorizes: spectral scalar s[bn,k] (packed: k<=256 real, k>256 imag)
//  mlp(s*emb) piecewise-linear in s (257 regions; tables Atab/Btab[r][e])
//  xt-part of flat@fw1:  h2[bn,h] = sum_{k,e} Yp[bn,k,e] * M2[k,e,h],
//      M2[k,(h,e)] = sum_t W[t,k] fw1[(t*128+e)*256+h]   (W = packed irfft basis)
//      Yp values are generated IN-REGISTER inside GEMM1 (fused softshrink), never materialized.
//  xn-part:   xn@F1s = hl@(tw2@F1s) + tb2@F1s,  F1s[t,h] = sum_e fw1
//  bias-part: x_noD@F1e,                        F1e[t,h] = sum_e (1+emb_e) fw1
//  s and x@F1e computed via hi/lo bf16 K-concat MFMA (A=[hi|lo|hi], B=[hi;hi;lo]) — G1,
//  now split-K over 8 chunks (grid 256) + reduce (the old grid-32 version was 40us at 1% occupancy).
// GEMM0/GEMM1 use global_load_lds (width 16) + source-pre-swizzled LDS (slot^(row&7)),
// double-buffered, ONE barrier per K-step, setprio around MFMA.
// h2b GEMM folded into k_final (deleted grid-8 dispatch).

typedef unsigned int uint;
typedef unsigned short ushort_t;
typedef __attribute__((ext_vector_type(4))) float f32x4;
typedef __attribute__((ext_vector_type(8))) short short8;

#define LAMBDA_ 0.001f
#define RSQRT512 0.044194173824159220f

__device__ __forceinline__ ushort_t f2bf(float f) {
    uint u = __float_as_uint(f);
    uint r = (u + 0x7FFFu + ((u >> 16) & 1u)) >> 16;
    return (ushort_t)r;
}
__device__ __forceinline__ float bf2f(ushort_t v) { return __uint_as_float(((uint)v) << 16); }
__device__ __forceinline__ float leaky_(float v) { return v >= 0.f ? v : 0.01f * v; }

__device__ __forceinline__ void gload_lds16(const ushort_t* g, ushort_t* l) {
    __builtin_amdgcn_global_load_lds((const __attribute__((address_space(1))) void*)g,
                                     (__attribute__((address_space(3))) void*)l, 16, 0, 0);
}

// ---------------- K_pre: merged setup(3072) | pack_tw1(32) | transpose_x(256); grid 3360 ----------------
__global__ __launch_bounds__(256) void k_pre(const float* __restrict__ x, const float* __restrict__ tw1,
                                             const float* __restrict__ tw2,
                                             ushort_t* __restrict__ A1cat, ushort_t* __restrict__ B1cat,
                                             ushort_t* __restrict__ Wt, ushort_t* __restrict__ tw2_bf) {
    __shared__ float tile[64 * 65];
    int bid = blockIdx.x;
    int tid = threadIdx.x;
    if (bid < 3072) {
        int region = bid >> 10;
        int id = ((bid & 1023) << 8) + tid;
        int a = id >> 9, c = id & 511;
        if (region == 0) {       // B1cat rows 0-511: D[t=c][k=a], hi|hi|lo
            int f = (a <= 256) ? a : (a - 256);
            int m = (c * f) & 511;
            float ang = (float)m * (6.283185307179586f / 512.0f);
            float v = ((a <= 256) ? cosf(ang) : -sinf(ang)) * RSQRT512;
            ushort_t hi = f2bf(v);
            ushort_t lo = f2bf(v - bf2f(hi));
            size_t row = (size_t)a * 1536;
            B1cat[row + c] = hi;
            B1cat[row + 512 + c] = hi;
            B1cat[row + 1024 + c] = lo;
        } else if (region == 1) {  // Wt[k=a][t=c]
            int f = (a <= 256) ? a : (a - 256);
            int m = (c * f) & 511;
            float ang = (float)m * (6.283185307179586f / 512.0f);
            float v = ((a <= 256) ? cosf(ang) : -sinf(ang)) * RSQRT512;
            float sc = (a == 0 || a == 256) ? 1.0f : 2.0f;
            Wt[id] = f2bf(v * sc);
        } else {                   // tw2_bf (512 blocks used)
            if ((bid & 1023) < 512) tw2_bf[id] = f2bf(tw2[id]);
        }
    } else if (bid < 3104) {
        // pack_tw1 -> B1cat rows 512-767 (transposed, hi|hi|lo)
        int b = bid - 3072;               // 8 t-tiles * 4 h-tiles
        int t0 = (b & 7) << 6, h0 = (b >> 3) << 6;
        float (*t64)[65] = (float(*)[65])tile;
        for (int i = 0; i < 16; ++i) {
            int idx = tid + i * 256;
            int r = idx >> 6, cc = idx & 63;
            t64[r][cc] = tw1[(size_t)(t0 + r) * 256 + h0 + cc];
        }
        __syncthreads();
        for (int i = 0; i < 16; ++i) {
            int idx = tid + i * 256;
            int rr = idx >> 6, cc2 = idx & 63;      // rr: h, cc2: t
            float v = t64[cc2][rr];
            ushort_t hi = f2bf(v);
            ushort_t lo = f2bf(v - bf2f(hi));
            size_t row = (size_t)(512 + h0 + rr) * 1536;
            int t = t0 + cc2;
            B1cat[row + t] = hi;
            B1cat[row + 512 + t] = hi;
            B1cat[row + 1024 + t] = lo;
        }
    } else {
        // transpose_x [8][512][64] -> A1cat [512 bn][1536] (hi|lo|hi)
        int b = bid - 3104;               // 256
        int bb = b >> 5;
        int rem = b & 31;
        int t0 = (rem >> 1) << 5;
        int n0 = (rem & 1) << 5;
        int tx = tid & 31, ty = tid >> 5;
        float (*t32)[33] = (float(*)[33])tile;
        for (int i = 0; i < 4; ++i) {
            int tt = ty * 4 + i;
            t32[tt][tx] = x[(size_t)(bb * 512 + t0 + tt) * 64 + n0 + tx];
        }
        __syncthreads();
        for (int i = 0; i < 4; ++i) {
            int nn = ty * 4 + i;
            float v = t32[tx][nn];
            ushort_t hi = f2bf(v);
            ushort_t lo = f2bf(v - bf2f(hi));
            size_t row = (size_t)(bb * 64 + n0 + nn) * 1536;
            int t = t0 + tx;
            A1cat[row + t] = hi;
            A1cat[row + 512 + t] = lo;
            A1cat[row + 1024 + t] = hi;
        }
    }
}

// ---------------- K3: piecewise-linear tables (1 block); w2 staged in LDS ----------------
__global__ __launch_bounds__(256) void k_prep(const float* __restrict__ emb, const float* __restrict__ w1,
                                              const float* __restrict__ b1, const float* __restrict__ w2,
                                              const float* __restrict__ b2,
                                              ushort_t* __restrict__ Atab, ushort_t* __restrict__ Btab,
                                              float* __restrict__ bpkey_g) {
    __shared__ float w2s[256 * 128];   // 128 KB
    __shared__ float u_s[256], b1_s[256], key_s[256];
    __shared__ int idx_s[256];
    int tid = threadIdx.x;
    for (int i = 0; i < 32; ++i) {
        int idx4 = tid + i * 256;
        *(float4*)&w2s[idx4 * 4] = *(const float4*)&w2[idx4 * 4];
    }
    float acc = 0.f;
    for (int e = 0; e < 128; ++e) acc += emb[e] * w1[e * 256 + tid];
    u_s[tid] = acc;
    float bb0 = b1[tid];
    b1_s[tid] = bb0;
    key_s[tid] = (acc == 0.f) ? INFINITY : (-bb0 / acc);
    idx_s[tid] = tid;
    __syncthreads();
    for (int k = 2; k <= 256; k <<= 1) {
        for (int j = k >> 1; j > 0; j >>= 1) {
            int ixj = tid ^ j;
            if (ixj > tid) {
                bool up = ((tid & k) == 0);
                float a0 = key_s[tid], a1 = key_s[ixj];
                if ((a0 > a1) == up) {
                    key_s[tid] = a1; key_s[ixj] = a0;
                    int t0 = idx_s[tid]; idx_s[tid] = idx_s[ixj]; idx_s[ixj] = t0;
                }
            }
            __syncthreads();
        }
    }
    bpkey_g[tid] = key_s[tid];
    if (tid < 128) {
        int e = tid;
        float aA = 0.f, aB = 0.f;
        for (int h = 0; h < 256; ++h) {
            float uu = u_s[h], bbh = b1_s[h];
            float c = (uu < 0.f || (uu == 0.f && bbh >= 0.f)) ? 1.0f : 0.01f;
            float w = w2s[h * 128 + e];
            aA += c * uu * w;
            aB += c * bbh * w;
        }
        aB += b2[e];
        Atab[e] = f2bf(aA);
        Btab[e] = f2bf(aB);
        for (int r = 1; r <= 256; ++r) {
            int h = idx_s[r - 1];
            float uu = u_s[h], bbh = b1_s[h];
            float w = w2s[h * 128 + e];
            float sgn = (uu > 0.f) ? 0.99f : -0.99f;
            aA += sgn * uu * w;
            aB += sgn * bbh * w;
            Atab[r * 128 + e] = f2bf(aA);
            Btab[r * 128 + e] = f2bf(aB);
        }
    }
}

// ---------------- K4: transpose fw1 [(t,e)][h] f32 -> fw1T[(h*128+e)][t] bf16 ----------------
__global__ __launch_bounds__(256) void k_transpose_fw1(const float* __restrict__ fw1, ushort_t* __restrict__ fw1T) {
    __shared__ float tile[64][65];
    int bid = blockIdx.x;
    int e  = bid & 127;
    int hb = (bid >> 7) & 3;
    int tt = bid >> 9;
    int t0 = tt << 6, h0 = hb << 6;
    int tid = threadIdx.x;
    for (int i = 0; i < 4; ++i) {
        int idx = tid + i * 256;            // 0..1023 float4s
        int r = idx >> 4, c4 = idx & 15;
        const float* src = fw1 + ((size_t)(t0 + r) * 128 + e) * 256 + h0 + c4 * 4;
        float4 v = *(const float4*)src;
        tile[r][c4 * 4 + 0] = v.x;
        tile[r][c4 * 4 + 1] = v.y;
        tile[r][c4 * 4 + 2] = v.z;
        tile[r][c4 * 4 + 3] = v.w;
    }
    __syncthreads();
    for (int p = 0; p < 2; ++p) {
        int idx = tid + p * 256;            // 0..511 short8s
        int hh = idx >> 3, tg = idx & 7;
        short8 o;
        for (int j = 0; j < 8; ++j) o[j] = (short)f2bf(tile[tg * 8 + j][hh]);
        *(short8*)(fw1T + ((size_t)(h0 + hh) * 128 + e) * 512 + t0 + tg * 8) = o;
    }
}

// ---------------- K4b: F1 from fw1T: F1T[0][h][t]=sum_e fw1T, F1T[1][h][t]=sum_e(1+emb)fw1T ----------------
__global__ __launch_bounds__(256) void k_reduce_F2(const ushort_t* __restrict__ fw1T, const float* __restrict__ emb,
                                                   float* __restrict__ F1T) {
    __shared__ float embs[128];
    int h = blockIdx.x;                  // 256
    int tid = threadIdx.x;
    if (tid < 128) embs[tid] = 1.f + emb[tid];
    __syncthreads();
    int t2 = tid * 2;
    const ushort_t* base = fw1T + ((size_t)h << 16) + t2;
    float as0 = 0.f, as1 = 0.f, ae0 = 0.f, ae1 = 0.f;
#pragma unroll 4
    for (int e = 0; e < 128; ++e) {
        uint v = *(const uint*)(base + (size_t)e * 512);
        float v0 = bf2f((ushort_t)(v & 0xffff));
        float v1 = bf2f((ushort_t)(v >> 16));
        float w = embs[e];
        as0 += v0; as1 += v1;
        ae0 += w * v0; ae1 += w * v1;
    }
    F1T[(size_t)h * 512 + t2] = as0;
    F1T[(size_t)h * 512 + t2 + 1] = as1;
    F1T[131072 + (size_t)h * 512 + t2] = ae0;
    F1T[131072 + (size_t)h * 512 + t2 + 1] = ae1;
}

// ---------------- K5: pack F1s/F1e: B1cat rows 768-1023 (F1e hi|hi|lo), F1sT_bf, p2v = tb2@F1s ----------------
__global__ __launch_bounds__(64) void k_pack_F(const float* __restrict__ F1sT, const float* __restrict__ F1eT,
                                               const float* __restrict__ tb2,
                                               ushort_t* __restrict__ B1cat, ushort_t* __restrict__ F1sT_bf,
                                               float* __restrict__ p2v) {
    int h = blockIdx.x;                   // 256
    int lane = threadIdx.x;
    int t = lane * 8;
    float p2 = 0.f;
    short8 shi, ehi, elo;
    for (int j = 0; j < 8; ++j) {
        float vs = F1sT[(size_t)h * 512 + t + j];
        float ve = F1eT[(size_t)h * 512 + t + j];
        p2 += tb2[t + j] * vs;
        shi[j] = (short)f2bf(vs);
        ushort_t hi = f2bf(ve);
        ehi[j] = (short)hi;
        elo[j] = (short)f2bf(ve - bf2f(hi));
    }
    *(short8*)(F1sT_bf + (size_t)h * 512 + t) = shi;
    size_t row = (size_t)(768 + h) * 1536;
    *(short8*)(B1cat + row + t) = ehi;
    *(short8*)(B1cat + row + 512 + t) = ehi;
    *(short8*)(B1cat + row + 1024 + t) = elo;
    for (int o = 32; o > 0; o >>= 1) p2 += __shfl_xor(p2, o);
    if (lane == 0) p2v[h] = p2;
}

// ---------------- K_g1: split-K G1 partials: partialG[kch] = A1cat @ B1cat^T chunk ----------------
// M=512, N=1024, K=1536 split into 8 chunks of 192 (3 kt of 64). grid 256 = kch(8) x [nt(8) x mt(4)].
__global__ __launch_bounds__(256) void k_g1(const ushort_t* __restrict__ A, const ushort_t* __restrict__ Bm,
                                            float* __restrict__ partialG) {
    __shared__ ushort_t As[128 * 72];
    __shared__ ushort_t Bs[128 * 72];
    int tid = threadIdx.x;
    int lane = tid & 63, wid = tid >> 6;
    int wr = wid >> 1, wc = wid & 1;
    int bid = blockIdx.x;
    int kch = bid & 7, tilei = bid >> 3;
    int nt = tilei & 7, mt = tilei >> 3;
    int m0 = mt * 128, n0 = nt * 128;
    f32x4 acc[4][4] = {};
    for (int kt = 0; kt < 3; ++kt) {
        int kb = kch * 192 + kt * 64;
        __syncthreads();
        {
            uint4 va[4], vb[4];
            for (int i = 0; i < 4; ++i) {
                int q = tid + i * 256;
                int row = q >> 3, kcc = (q & 7) << 3;
                va[i] = *(const uint4*)(A + (size_t)(m0 + row) * 1536 + kb + kcc);
                vb[i] = *(const uint4*)(Bm + (size_t)(n0 + row) * 1536 + kb + kcc);
            }
            for (int i = 0; i < 4; ++i) {
                int q = tid + i * 256;
                int row = q >> 3, kcc = (q & 7) << 3;
                *(uint4*)&As[row * 72 + kcc] = va[i];
                *(uint4*)&Bs[row * 72 + kcc] = vb[i];
            }
        }
        __syncthreads();
        for (int ks = 0; ks < 2; ++ks) {
            short8 a[4], b[4];
            int kk = ks * 32 + (lane >> 4) * 8;
            for (int mi = 0; mi < 4; ++mi)
                a[mi] = *(const short8*)&As[(wr * 64 + mi * 16 + (lane & 15)) * 72 + kk];
            for (int ni = 0; ni < 4; ++ni)
                b[ni] = *(const short8*)&Bs[(wc * 64 + ni * 16 + (lane & 15)) * 72 + kk];
            for (int mi = 0; mi < 4; ++mi)
                for (int ni = 0; ni < 4; ++ni)
                    acc[mi][ni] = __builtin_amdgcn_mfma_f32_16x16x32_bf16(a[mi], b[ni], acc[mi][ni], 0, 0, 0);
        }
    }
    float* pbase = partialG + (size_t)kch * 524288;
    int mb0 = m0 + wr * 64 + ((lane >> 4) << 2);
    int nb0 = n0 + wc * 64 + (lane & 15);
    for (int mi = 0; mi < 4; ++mi)
        for (int ni = 0; ni < 4; ++ni) {
            int mbase = mb0 + mi * 16;
            int n = nb0 + ni * 16;
            for (int r = 0; r < 4; ++r)
                pbase[(size_t)(mbase + r) * 1024 + n] = acc[mi][ni][r];
        }
}

// ---------------- K_reduceG1: sum 8 partials, route epilogue to s / hl / h2c ----------------
__global__ __launch_bounds__(256) void k_reduceG1(const float* __restrict__ partialG, const float* __restrict__ tb1,
                                                  float* __restrict__ s, ushort_t* __restrict__ hl,
                                                  float* __restrict__ h2c) {
    int id = blockIdx.x * 256 + threadIdx.x;   // grid 2048 -> 524288
    int m = id >> 10, n = id & 1023;
    float acc = 0.f;
#pragma unroll
    for (int kc = 0; kc < 8; ++kc)
        acc += partialG[(size_t)kc * 524288 + id];
    if (n < 512) s[(size_t)m * 512 + n] = acc;
    else if (n < 768) hl[(size_t)m * 256 + (n - 512)] = f2bf(leaky_(acc + tb1[n - 512]));
    else h2c[(size_t)m * 256 + (n - 768)] = acc;
}

// ---------------- K_p2: P2T = (tw2 @ F1s^T)^T store; M=N=256, K=512; grid 4 ----------------
__global__ __launch_bounds__(256) void k_p2(const ushort_t* __restrict__ A, const ushort_t* __restrict__ Bm,
                                            ushort_t* __restrict__ P2T) {
    __shared__ ushort_t As[128 * 72];
    __shared__ ushort_t Bs[128 * 72];
    int tid = threadIdx.x;
    int lane = tid & 63, wid = tid >> 6;
    int wr = wid >> 1, wc = wid & 1;
    int bid = blockIdx.x;
    int nt = bid & 1, mt = bid >> 1;
    int m0 = mt * 128, n0 = nt * 128;
    f32x4 acc[4][4] = {};
    for (int kt = 0; kt < 8; ++kt) {
        int kb = kt * 64;
        __syncthreads();
        {
            uint4 va[4], vb[4];
            for (int i = 0; i < 4; ++i) {
                int q = tid + i * 256;
                int row = q >> 3, kcc = (q & 7) << 3;
                va[i] = *(const uint4*)(A + (size_t)(m0 + row) * 512 + kb + kcc);
                vb[i] = *(const uint4*)(Bm + (size_t)(n0 + row) * 512 + kb + kcc);
            }
            for (int i = 0; i < 4; ++i) {
                int q = tid + i * 256;
                int row = q >> 3, kcc = (q & 7) << 3;
                *(uint4*)&As[row * 72 + kcc] = va[i];
                *(uint4*)&Bs[row * 72 + kcc] = vb[i];
            }
        }
        __syncthreads();
        for (int ks = 0; ks < 2; ++ks) {
            short8 a[4], b[4];
            int kk = ks * 32 + (lane >> 4) * 8;
            for (int mi = 0; mi < 4; ++mi)
                a[mi] = *(const short8*)&As[(wr * 64 + mi * 16 + (lane & 15)) * 72 + kk];
            for (int ni = 0; ni < 4; ++ni)
                b[ni] = *(const short8*)&Bs[(wc * 64 + ni * 16 + (lane & 15)) * 72 + kk];
            for (int mi = 0; mi < 4; ++mi)
                for (int ni = 0; ni < 4; ++ni)
                    acc[mi][ni] = __builtin_amdgcn_mfma_f32_16x16x32_bf16(a[mi], b[ni], acc[mi][ni], 0, 0, 0);
        }
    }
    int mb0 = m0 + wr * 64 + ((lane >> 4) << 2);
    int nb0 = n0 + wc * 64 + (lane & 15);
    for (int mi = 0; mi < 4; ++mi)
        for (int ni = 0; ni < 4; ++ni) {
            int mbase = mb0 + mi * 16;
            int n = nb0 + ni * 16;
            ushort4 o;
            o.x = f2bf(acc[mi][ni][0]);
            o.y = f2bf(acc[mi][ni][1]);
            o.z = f2bf(acc[mi][ni][2]);
            o.w = f2bf(acc[mi][ni][3]);
            *(ushort4*)(P2T + (size_t)n * 256 + mbase) = o;
        }
}

// ---------------- GEMM0: M2T = Wt @ fw1T^T (M=512, N=32768, K=512) ----------------
__global__ __launch_bounds__(512) void k_gemm0(const ushort_t* __restrict__ A, const ushort_t* __restrict__ Bm,
                                               ushort_t* __restrict__ M2T) {
    __shared__ ushort_t As[2][128 * 64];
    __shared__ ushort_t Bs[2][128 * 64];
    int tid = threadIdx.x;
    int lane = tid & 63, wid = tid >> 6;
    int wr = wid >> 2, wc = wid & 3;          // 2 x 4 waves; wave tile 64m x 32n
    int bid = blockIdx.x;
    int xx = bid & 7, y = bid >> 3;
    int mt = y & 3;
    int nt = ((y >> 2) << 3) | xx;
    int m0 = mt * 128, n0 = nt * 128;
    int lrow = lane >> 3;                     // 0..7
    int sg = (lane & 7) ^ lrow;               // swizzled source 16B-slot
    auto issue = [&](int kt, int buf) {
        int kb = kt * 64;
        for (int i = 0; i < 2; ++i) {
            int rbase = wid * 16 + i * 8;
            gload_lds16(A + (size_t)(m0 + rbase + lrow) * 512 + kb + sg * 8, &As[buf][wid * 1024 + i * 512]);
            gload_lds16(Bm + (size_t)(n0 + rbase + lrow) * 512 + kb + sg * 8, &Bs[buf][wid * 1024 + i * 512]);
        }
    };
    f32x4 acc[4][2] = {};
    issue(0, 0);
    __syncthreads();
    int cur = 0;
    for (int kt = 0; kt < 8; ++kt) {
        int nxt = cur ^ 1;
        if (kt + 1 < 8) issue(kt + 1, nxt);
        __builtin_amdgcn_s_setprio(1);
        for (int ks = 0; ks < 2; ++ks) {
            short8 a[4], b[2];
            int sl = ks * 4 + (lane >> 4);
            for (int mi = 0; mi < 4; ++mi) {
                int row = wr * 64 + mi * 16 + (lane & 15);
                a[mi] = *(const short8*)&As[cur][row * 64 + ((sl ^ (row & 7)) << 3)];
            }
            for (int ni = 0; ni < 2; ++ni) {
                int row = wc * 32 + ni * 16 + (lane & 15);
                b[ni] = *(const short8*)&Bs[cur][row * 64 + ((sl ^ (row & 7)) << 3)];
            }
            for (int mi = 0; mi < 4; ++mi)
                for (int ni = 0; ni < 2; ++ni)
                    acc[mi][ni] = __builtin_amdgcn_mfma_f32_16x16x32_bf16(a[mi], b[ni], acc[mi][ni], 0, 0, 0);
        }
        __builtin_amdgcn_s_setprio(0);
        __syncthreads();
        cur = nxt;
    }
    // epilogue: stage 128x128 bf16 C tile across As[0..1] (exactly 32KB), swizzled, then linear copy
    ushort_t* cstage = &As[0][0];
    for (int mi = 0; mi < 4; ++mi) {
        int ml = wr * 64 + mi * 16 + ((lane >> 4) << 2);
        for (int ni = 0; ni < 2; ++ni) {
            int nl = wc * 32 + ni * 16 + (lane & 15);
            for (int r = 0; r < 4; ++r) {
                int row = ml + r;
                cstage[row * 128 + (nl ^ ((row & 7) << 4))] = f2bf(acc[mi][ni][r]);
            }
        }
    }
    __syncthreads();
    short8* d8 = (short8*)(M2T + ((size_t)(n0 >> 7) << 16) + (size_t)m0 * 128);
    for (int i = 0; i < 4; ++i) {
        int p = tid + i * 512;                 // short8 index 0..2047
        int row = p >> 4;
        int col0 = (p & 15) * 8;
        d8[p] = *(const short8*)&cstage[row * 128 + (col0 ^ ((row & 7) << 4))];
    }
}

// ---------------- GEMM1 (fused): partial[kc] = cook(s) @ M2T^T chunk ----------------
__global__ __launch_bounds__(512) void k_gemm1(const float* __restrict__ s,
                                               const ushort_t* __restrict__ Atab, const ushort_t* __restrict__ Btab,
                                               const float* __restrict__ bpkey,
                                               const ushort_t* __restrict__ Bm,
                                               float* __restrict__ partial) {
    __shared__ ushort_t As[2][128 * 64];
    __shared__ ushort_t Bs[2][128 * 64];
    __shared__ float sv_s[1024];
    __shared__ ushort_t r_s[1024];
    __shared__ float bp_s[256];
    int tid = threadIdx.x;
    int lane = tid & 63, wid = tid >> 6;
    int wr = wid >> 2, wc = wid & 3;           // 2 x 4 waves; wave tile 64m x 32n
    int bid = blockIdx.x;
    int xcd = bid & 7, j = bid >> 3;           // j: 0..63
    int kcl = j & 7, mt = (j >> 3) & 3, nt = j >> 5;
    int kc = xcd * 8 + kcl;                    // 0..63
    int m0 = mt * 128, n0 = nt * 128;
    int k0 = kc * 1024;
    if (tid < 256) bp_s[tid] = bpkey[tid];
    __syncthreads();
    {   // stage s-slice (128 rows x 8 k) + region lookup: 512 thr x float2
        int row = tid >> 2, j2 = (tid & 3) * 2;
        float2 sv2 = *(const float2*)(s + (size_t)(m0 + row) * 512 + kc * 8 + j2);
        float svv[2] = {sv2.x, sv2.y};
        for (int q = 0; q < 2; ++q) {
            float sv = svv[q];
            int lo = 0, hi = 256;
            while (lo < hi) { int mid = (lo + hi) >> 1; if (bp_s[mid] <= sv) lo = mid + 1; else hi = mid; }
            sv_s[row * 8 + j2 + q] = sv;
            r_s[row * 8 + j2 + q] = (ushort_t)lo;
        }
    }
    __syncthreads();

    int lrow = lane >> 3;
    int sg = (lane & 7) ^ lrow;
    auto issueB = [&](int kt, int buf) {
        int kb = k0 + kt * 64;
        for (int i = 0; i < 2; ++i) {
            int rbase = wid * 16 + i * 8;
            gload_lds16(Bm + (size_t)(n0 + rbase + lrow) * 65536 + kb + sg * 8, &Bs[buf][wid * 1024 + i * 512]);
        }
    };
    short8 ta[2], tb[2];
    float svr[2];
    auto gather = [&](int kt) {
        int kl = kt >> 1;
        for (int i = 0; i < 2; ++i) {
            int q = tid + i * 512;
            int row = q >> 3, slot = q & 7;
            int e0 = ((kt & 1) << 6) + slot * 8;
            int r = r_s[row * 8 + kl];
            svr[i] = sv_s[row * 8 + kl];
            ta[i] = *(const short8*)(Atab + r * 128 + e0);
            tb[i] = *(const short8*)(Btab + r * 128 + e0);
        }
    };
    auto cookwrite = [&](int buf) {
        for (int i = 0; i < 2; ++i) {
            int q = tid + i * 512;
            int row = q >> 3, slot = q & 7;
            float sv = svr[i];
            short8 o;
            for (int jj = 0; jj < 8; ++jj) {
                float y = fmaf(sv, bf2f((ushort_t)ta[i][jj]), bf2f((ushort_t)tb[i][jj]));
                y = y - fminf(fmaxf(y, -LAMBDA_), LAMBDA_);
                o[jj] = (short)f2bf(y);
            }
            *(short8*)&As[buf][row * 64 + ((slot ^ (row & 7)) << 3)] = o;
        }
    };

    f32x4 acc[4][2] = {};
    issueB(0, 0);
    gather(0);
    cookwrite(0);
    __syncthreads();
    int cur = 0;
    for (int kt = 0; kt < 16; ++kt) {
        int nxt = cur ^ 1;
        if (kt + 1 < 16) { issueB(kt + 1, nxt); gather(kt + 1); }
        __builtin_amdgcn_s_setprio(1);
        for (int ks = 0; ks < 2; ++ks) {
            short8 a[4], b[2];
            int sl = ks * 4 + (lane >> 4);
            for (int mi = 0; mi < 4; ++mi) {
                int row = wr * 64 + mi * 16 + (lane & 15);
                a[mi] = *(const short8*)&As[cur][row * 64 + ((sl ^ (row & 7)) << 3)];
            }
            for (int ni = 0; ni < 2; ++ni) {
                int row = wc * 32 + ni * 16 + (lane & 15);
                b[ni] = *(const short8*)&Bs[cur][row * 64 + ((sl ^ (row & 7)) << 3)];
            }
            for (int mi = 0; mi < 4; ++mi)
                for (int ni = 0; ni < 2; ++ni)
                    acc[mi][ni] = __builtin_amdgcn_mfma_f32_16x16x32_bf16(a[mi], b[ni], acc[mi][ni], 0, 0, 0);
        }
        __builtin_amdgcn_s_setprio(0);
        if (kt + 1 < 16) cookwrite(nxt);
        __syncthreads();
        cur = nxt;
    }
    int mb0 = m0 + wr * 64 + ((lane >> 4) << 2);
    int nb0 = wc * 32 + (lane & 15);
    float* pbase = partial + (size_t)kc * 131072 + n0;
    for (int mi = 0; mi < 4; ++mi)
        for (int ni = 0; ni < 2; ++ni) {
            int mbase = mb0 + mi * 16;
            int n = nb0 + ni * 16;
            for (int r = 0; r < 4; ++r)
                pbase[(size_t)(mbase + r) * 256 + n] = acc[mi][ni][r];
        }
}

// ---------------- K10: final: h2b-row (hl@P2T) computed inline; a=leaky(sum+...); out=a@fw2+fb2 ----------------
__global__ __launch_bounds__(128) void k_final(const float* __restrict__ partial, const ushort_t* __restrict__ hl,
                                               const ushort_t* __restrict__ P2T, const float* __restrict__ p2v,
                                               const float* __restrict__ h2c, const float* __restrict__ fb1,
                                               const float* __restrict__ fw2, const float* __restrict__ fb2,
                                               float* __restrict__ out) {
    __shared__ float a_s[256];
    __shared__ float hl_s[256];
    int bn = blockIdx.x;
    int tid = threadIdx.x;
    {
        uint v = *(const uint*)(hl + (size_t)bn * 256 + tid * 2);
        hl_s[tid * 2] = bf2f((ushort_t)(v & 0xffff));
        hl_s[tid * 2 + 1] = bf2f((ushort_t)(v >> 16));
    }
    __syncthreads();
    for (int p = 0; p < 2; ++p) {
        int i = tid + p * 128;
        float acc = p2v[i] + h2c[(size_t)bn * 256 + i] + fb1[i];
#pragma unroll 8
        for (int kc = 0; kc < 64; ++kc)
            acc += partial[((size_t)kc * 512 + bn) * 256 + i];
        const ushort_t* prow = P2T + (size_t)i * 256;
#pragma unroll 4
        for (int jb = 0; jb < 32; ++jb) {
            short8 pv = *(const short8*)(prow + jb * 8);
            for (int j8 = 0; j8 < 8; ++j8)
                acc += hl_s[jb * 8 + j8] * bf2f((ushort_t)pv[j8]);
        }
        a_s[i] = leaky_(acc);
    }
    __syncthreads();
    if (tid < 96) {
        float acc = fb2[tid];
        for (int hh = 0; hh < 256; ++hh)
            acc += a_s[hh] * fw2[hh * 96 + tid];
        int b = bn >> 6, n = bn & 63;
        out[(size_t)(b * 96 + tid) * 64 + n] = acc;
    }
}

extern "C" void kernel_launch(void* const* d_in, const int* in_sizes, int n_in,
                              void* d_out, int out_size, void* d_ws, size_t ws_size,
                              hipStream_t stream) {
    const float* x   = (const float*)d_in[0];
    const float* emb = (const float*)d_in[1];
    const float* w1  = (const float*)d_in[2];
    const float* b1  = (const float*)d_in[3];
    const float* w2  = (const float*)d_in[4];
    const float* b2  = (const float*)d_in[5];
    const float* tw1 = (const float*)d_in[6];
    const float* tb1 = (const float*)d_in[7];
    const float* tw2 = (const float*)d_in[8];
    const float* tb2 = (const float*)d_in[9];
    const float* fw1 = (const float*)d_in[10];
    const float* fb1 = (const float*)d_in[11];
    const float* fw2 = (const float*)d_in[12];
    const float* fb2 = (const float*)d_in[13];
    float* out = (float*)d_out;

    char* W = (char*)d_ws;
    size_t off = 0;
    auto take = [&](size_t bytes) { size_t r = off; off += (bytes + 255) & ~(size_t)255; return r; };
    ushort_t* fw1T  = (ushort_t*)(W + take(33554432));        // [32768 j''=h*128+e][512 t] bf16
    ushort_t* M2T   = (ushort_t*)(W + take(33554432));        // [256 h][65536 k'] bf16
    float* partial  = (float*)(W + take(64 * 512 * 256 * 4)); // [64 kc][512 bn][256 h] f32
    float* partialG = (float*)(W + take(8 * 512 * 1024 * 4)); // [8 kch][512 bn][1024 n] f32
    ushort_t* A1cat = (ushort_t*)(W + take(512 * 1536 * 2));
    ushort_t* B1cat = (ushort_t*)(W + take(1024 * 1536 * 2));
    ushort_t* Wt    = (ushort_t*)(W + take(512 * 512 * 2));
    ushort_t* tw2bf = (ushort_t*)(W + take(256 * 512 * 2));
    float* F1T      = (float*)(W + take(2 * 256 * 512 * 4)); // [2][h][t]
    ushort_t* F1sbf = (ushort_t*)(W + take(256 * 512 * 2));
    float* sbuf     = (float*)(W + take(512 * 512 * 4));
    ushort_t* hlbuf = (ushort_t*)(W + take(512 * 256 * 2));
    float* h2c      = (float*)(W + take(512 * 256 * 4));
    ushort_t* P2T   = (ushort_t*)(W + take(256 * 256 * 2));
    float* p2v      = (float*)(W + take(256 * 4));
    ushort_t* Atab  = (ushort_t*)(W + take(257 * 128 * 2));
    ushort_t* Btab  = (ushort_t*)(W + take(257 * 128 * 2));
    float* bpkey    = (float*)(W + take(256 * 4));
    (void)ws_size; (void)in_sizes; (void)n_in; (void)out_size;

    // merged setup | pack_tw1 | transpose_x
    k_pre<<<3360, 256, 0, stream>>>(x, tw1, tw2, A1cat, B1cat, Wt, tw2bf);
    k_prep<<<1, 256, 0, stream>>>(emb, w1, b1, w2, b2, Atab, Btab, bpkey);
    k_transpose_fw1<<<4096, 256, 0, stream>>>(fw1, fw1T);
    k_reduce_F2<<<256, 256, 0, stream>>>(fw1T, emb, F1T);
    k_pack_F<<<256, 64, 0, stream>>>(F1T, F1T + 131072, tb2, B1cat, F1sbf, p2v);
    // G1 split-K: partialG[kch] = xTcat @ B1cat^T chunk  (M=512, N=1024, K=1536/8)
    k_g1<<<256, 256, 0, stream>>>(A1cat, B1cat, partialG);
    k_reduceG1<<<2048, 256, 0, stream>>>(partialG, tb1, sbuf, hlbuf, h2c);
    // GEMM0: M2T = Wt @ fw1T^T  (M=512 k, N=32768 j'', K=512 t)
    k_gemm0<<<1024, 512, 0, stream>>>(Wt, fw1T, M2T);
    // P2' = tw2 @ F1s  (M=256, N=256, K=512) -> P2T
    k_p2<<<4, 256, 0, stream>>>(tw2bf, F1sbf, P2T);
    // GEMM1 (fused softshrink-A): partial[kc] = cook(s) @ M2T^T  (split-K 64)
    k_gemm1<<<512, 512, 0, stream>>>(sbuf, Atab, Btab, bpkey, M2T, partial);
    // final (h2b GEMM folded in)
    k_final<<<512, 128, 0, stream>>>(partial, hlbuf, P2T, p2v, h2c, fb1, fw2, fb2, out);
}

// Round 11
// 164.833 us; speedup vs baseline: 2.0030x; 1.1192x over previous
//
#include <hip/hip_runtime.h>
#include <hip/hip_bf16.h>

// B=8, T=512, N=64, E=128, H=256, P=96.  bn = b*64+n (512 rows).
// Identities:
//  xe = x_noD*emb  => rfft factorizes: spectral scalar s[bn,k] (packed: k<=256 real, k>256 imag)
//  mlp(s*emb) piecewise-linear in s (257 regions; tables Atab/Btab[r][e])
//  xt-part of flat@fw1:  h2[bn,h] = sum_{k,e} Yp[bn,k,e] * M2[k,e,h],
//      M2[k,(h,e)] = sum_t W[t,k] fw1[(t*128+e)*256+h]   (W = packed irfft basis)
//      Yp values are generated IN-REGISTER inside GEMM1 (fused softshrink), never materialized.
//  xn-part:   xn@F1s = hl@(tw2@F1s) + tb2@F1s,  F1s[t,h] = sum_e fw1
//  bias-part: x_noD@F1e,                        F1e[t,h] = sum_e (1+emb_e) fw1
//  s and x@F1e computed via hi/lo bf16 K-concat MFMA (A=[hi|lo|hi], B=[hi;hi;lo]) — G1 split-K.
// Round 11: k_prep (38.6us, 1 block, latency-bound serial scan) parallelized into
//  k_prep1 (sort only) + k_prep2 (grid-128 prefix-scan table build).

typedef unsigned int uint;
typedef unsigned short ushort_t;
typedef __attribute__((ext_vector_type(4))) float f32x4;
typedef __attribute__((ext_vector_type(8))) short short8;

#define LAMBDA_ 0.001f
#define RSQRT512 0.044194173824159220f

__device__ __forceinline__ ushort_t f2bf(float f) {
    uint u = __float_as_uint(f);
    uint r = (u + 0x7FFFu + ((u >> 16) & 1u)) >> 16;
    return (ushort_t)r;
}
__device__ __forceinline__ float bf2f(ushort_t v) { return __uint_as_float(((uint)v) << 16); }
__device__ __forceinline__ float leaky_(float v) { return v >= 0.f ? v : 0.01f * v; }

__device__ __forceinline__ void gload_lds16(const ushort_t* g, ushort_t* l) {
    __builtin_amdgcn_global_load_lds((const __attribute__((address_space(1))) void*)g,
                                     (__attribute__((address_space(3))) void*)l, 16, 0, 0);
}

// ---------------- K_pre: merged setup(3072) | pack_tw1(32) | transpose_x(256); grid 3360 ----------------
__global__ __launch_bounds__(256) void k_pre(const float* __restrict__ x, const float* __restrict__ tw1,
                                             const float* __restrict__ tw2,
                                             ushort_t* __restrict__ A1cat, ushort_t* __restrict__ B1cat,
                                             ushort_t* __restrict__ Wt, ushort_t* __restrict__ tw2_bf) {
    __shared__ float tile[64 * 65];
    int bid = blockIdx.x;
    int tid = threadIdx.x;
    if (bid < 3072) {
        int region = bid >> 10;
        int id = ((bid & 1023) << 8) + tid;
        int a = id >> 9, c = id & 511;
        if (region == 0) {       // B1cat rows 0-511: D[t=c][k=a], hi|hi|lo
            int f = (a <= 256) ? a : (a - 256);
            int m = (c * f) & 511;
            float ang = (float)m * (6.283185307179586f / 512.0f);
            float v = ((a <= 256) ? cosf(ang) : -sinf(ang)) * RSQRT512;
            ushort_t hi = f2bf(v);
            ushort_t lo = f2bf(v - bf2f(hi));
            size_t row = (size_t)a * 1536;
            B1cat[row + c] = hi;
            B1cat[row + 512 + c] = hi;
            B1cat[row + 1024 + c] = lo;
        } else if (region == 1) {  // Wt[k=a][t=c]
            int f = (a <= 256) ? a : (a - 256);
            int m = (c * f) & 511;
            float ang = (float)m * (6.283185307179586f / 512.0f);
            float v = ((a <= 256) ? cosf(ang) : -sinf(ang)) * RSQRT512;
            float sc = (a == 0 || a == 256) ? 1.0f : 2.0f;
            Wt[id] = f2bf(v * sc);
        } else {                   // tw2_bf (512 blocks used)
            if ((bid & 1023) < 512) tw2_bf[id] = f2bf(tw2[id]);
        }
    } else if (bid < 3104) {
        // pack_tw1 -> B1cat rows 512-767 (transposed, hi|hi|lo)
        int b = bid - 3072;               // 8 t-tiles * 4 h-tiles
        int t0 = (b & 7) << 6, h0 = (b >> 3) << 6;
        float (*t64)[65] = (float(*)[65])tile;
        for (int i = 0; i < 16; ++i) {
            int idx = tid + i * 256;
            int r = idx >> 6, cc = idx & 63;
            t64[r][cc] = tw1[(size_t)(t0 + r) * 256 + h0 + cc];
        }
        __syncthreads();
        for (int i = 0; i < 16; ++i) {
            int idx = tid + i * 256;
            int rr = idx >> 6, cc2 = idx & 63;      // rr: h, cc2: t
            float v = t64[cc2][rr];
            ushort_t hi = f2bf(v);
            ushort_t lo = f2bf(v - bf2f(hi));
            size_t row = (size_t)(512 + h0 + rr) * 1536;
            int t = t0 + cc2;
            B1cat[row + t] = hi;
            B1cat[row + 512 + t] = hi;
            B1cat[row + 1024 + t] = lo;
        }
    } else {
        // transpose_x [8][512][64] -> A1cat [512 bn][1536] (hi|lo|hi)
        int b = bid - 3104;               // 256
        int bb = b >> 5;
        int rem = b & 31;
        int t0 = (rem >> 1) << 5;
        int n0 = (rem & 1) << 5;
        int tx = tid & 31, ty = tid >> 5;
        float (*t32)[33] = (float(*)[33])tile;
        for (int i = 0; i < 4; ++i) {
            int tt = ty * 4 + i;
            t32[tt][tx] = x[(size_t)(bb * 512 + t0 + tt) * 64 + n0 + tx];
        }
        __syncthreads();
        for (int i = 0; i < 4; ++i) {
            int nn = ty * 4 + i;
            float v = t32[tx][nn];
            ushort_t hi = f2bf(v);
            ushort_t lo = f2bf(v - bf2f(hi));
            size_t row = (size_t)(bb * 64 + n0 + nn) * 1536;
            int t = t0 + tx;
            A1cat[row + t] = hi;
            A1cat[row + 512 + t] = lo;
            A1cat[row + 1024 + t] = hi;
        }
    }
}

// ---------------- K_prep1: u = emb@w1, breakpoint keys, bitonic sort (1 block) ----------------
__global__ __launch_bounds__(256) void k_prep1(const float* __restrict__ emb, const float* __restrict__ w1,
                                               const float* __restrict__ b1,
                                               float* __restrict__ u_g, int* __restrict__ idxs_g,
                                               float* __restrict__ bpkey_g) {
    __shared__ float key_s[256];
    __shared__ int idx_s[256];
    int tid = threadIdx.x;
    float acc = 0.f;
#pragma unroll 8
    for (int e = 0; e < 128; ++e) acc += emb[e] * w1[e * 256 + tid];
    u_g[tid] = acc;
    float bb0 = b1[tid];
    key_s[tid] = (acc == 0.f) ? INFINITY : (-bb0 / acc);
    idx_s[tid] = tid;
    __syncthreads();
    for (int k = 2; k <= 256; k <<= 1) {
        for (int j = k >> 1; j > 0; j >>= 1) {
            int ixj = tid ^ j;
            if (ixj > tid) {
                bool up = ((tid & k) == 0);
                float a0 = key_s[tid], a1 = key_s[ixj];
                if ((a0 > a1) == up) {
                    key_s[tid] = a1; key_s[ixj] = a0;
                    int t0 = idx_s[tid]; idx_s[tid] = idx_s[ixj]; idx_s[ixj] = t0;
                }
            }
            __syncthreads();
        }
    }
    bpkey_g[tid] = key_s[tid];
    idxs_g[tid] = idx_s[tid];
}

// ---------------- K_prep2: per-e prefix-scan table build (grid 128 = one block per e) ----------------
// Atab[r][e] = base_e + sum_{j<r} delta_e(idx[j]);  delta = sgn*u*w2[h][e], sgn=+-0.99.
__global__ __launch_bounds__(256) void k_prep2(const float* __restrict__ u_g, const float* __restrict__ b1,
                                               const float* __restrict__ w2, const float* __restrict__ b2,
                                               const int* __restrict__ idxs_g,
                                               ushort_t* __restrict__ Atab, ushort_t* __restrict__ Btab) {
    __shared__ float sA[256], sB[256];
    int e = blockIdx.x, r = threadIdx.x;
    // base (region 0) contribution of h'=r
    float uu0 = u_g[r], bb0 = b1[r];
    float w0 = w2[r * 128 + e];
    float c = (uu0 < 0.f || (uu0 == 0.f && bb0 >= 0.f)) ? 1.0f : 0.01f;
    float bA = c * uu0 * w0, bB = c * bb0 * w0;
    // delta of sorted position r
    int h = idxs_g[r];
    float uu = u_g[h], bb = b1[h];
    float w = w2[h * 128 + e];
    float sgn = (uu > 0.f) ? 0.99f : -0.99f;
    float dA = sgn * uu * w, dB = sgn * bb * w;
    // tree-reduce base
    sA[r] = bA; sB[r] = bB;
    __syncthreads();
    for (int off = 128; off > 0; off >>= 1) {
        if (r < off) { sA[r] += sA[r + off]; sB[r] += sB[r + off]; }
        __syncthreads();
    }
    float baseA = sA[0], baseB = sB[0] + b2[e];
    __syncthreads();
    // Hillis-Steele inclusive scan of deltas
    sA[r] = dA; sB[r] = dB;
    __syncthreads();
    for (int off = 1; off < 256; off <<= 1) {
        float vA = (r >= off) ? sA[r - off] : 0.f;
        float vB = (r >= off) ? sB[r - off] : 0.f;
        __syncthreads();
        sA[r] += vA; sB[r] += vB;
        __syncthreads();
    }
    if (r == 0) { Atab[e] = f2bf(baseA); Btab[e] = f2bf(baseB); }
    Atab[(r + 1) * 128 + e] = f2bf(baseA + sA[r]);
    Btab[(r + 1) * 128 + e] = f2bf(baseB + sB[r]);
}

// ---------------- K4: transpose fw1 [(t,e)][h] f32 -> fw1T[(h*128+e)][t] bf16 ----------------
__global__ __launch_bounds__(256) void k_transpose_fw1(const float* __restrict__ fw1, ushort_t* __restrict__ fw1T) {
    __shared__ float tile[64][65];
    int bid = blockIdx.x;
    int e  = bid & 127;
    int hb = (bid >> 7) & 3;
    int tt = bid >> 9;
    int t0 = tt << 6, h0 = hb << 6;
    int tid = threadIdx.x;
    for (int i = 0; i < 4; ++i) {
        int idx = tid + i * 256;            // 0..1023 float4s
        int r = idx >> 4, c4 = idx & 15;
        const float* src = fw1 + ((size_t)(t0 + r) * 128 + e) * 256 + h0 + c4 * 4;
        float4 v = *(const float4*)src;
        tile[r][c4 * 4 + 0] = v.x;
        tile[r][c4 * 4 + 1] = v.y;
        tile[r][c4 * 4 + 2] = v.z;
        tile[r][c4 * 4 + 3] = v.w;
    }
    __syncthreads();
    for (int p = 0; p < 2; ++p) {
        int idx = tid + p * 256;            // 0..511 short8s
        int hh = idx >> 3, tg = idx & 7;
        short8 o;
        for (int j = 0; j < 8; ++j) o[j] = (short)f2bf(tile[tg * 8 + j][hh]);
        *(short8*)(fw1T + ((size_t)(h0 + hh) * 128 + e) * 512 + t0 + tg * 8) = o;
    }
}

// ---------------- K4b: F1 from fw1T: F1T[0][h][t]=sum_e fw1T, F1T[1][h][t]=sum_e(1+emb)fw1T ----------------
__global__ __launch_bounds__(256) void k_reduce_F2(const ushort_t* __restrict__ fw1T, const float* __restrict__ emb,
                                                   float* __restrict__ F1T) {
    __shared__ float embs[128];
    int h = blockIdx.x;                  // 256
    int tid = threadIdx.x;
    if (tid < 128) embs[tid] = 1.f + emb[tid];
    __syncthreads();
    int t2 = tid * 2;
    const ushort_t* base = fw1T + ((size_t)h << 16) + t2;
    float as0 = 0.f, as1 = 0.f, ae0 = 0.f, ae1 = 0.f;
#pragma unroll 4
    for (int e = 0; e < 128; ++e) {
        uint v = *(const uint*)(base + (size_t)e * 512);
        float v0 = bf2f((ushort_t)(v & 0xffff));
        float v1 = bf2f((ushort_t)(v >> 16));
        float w = embs[e];
        as0 += v0; as1 += v1;
        ae0 += w * v0; ae1 += w * v1;
    }
    F1T[(size_t)h * 512 + t2] = as0;
    F1T[(size_t)h * 512 + t2 + 1] = as1;
    F1T[131072 + (size_t)h * 512 + t2] = ae0;
    F1T[131072 + (size_t)h * 512 + t2 + 1] = ae1;
}

// ---------------- K5: pack F1s/F1e: B1cat rows 768-1023 (F1e hi|hi|lo), F1sT_bf, p2v = tb2@F1s ----------------
__global__ __launch_bounds__(64) void k_pack_F(const float* __restrict__ F1sT, const float* __restrict__ F1eT,
                                               const float* __restrict__ tb2,
                                               ushort_t* __restrict__ B1cat, ushort_t* __restrict__ F1sT_bf,
                                               float* __restrict__ p2v) {
    int h = blockIdx.x;                   // 256
    int lane = threadIdx.x;
    int t = lane * 8;
    float p2 = 0.f;
    short8 shi, ehi, elo;
    for (int j = 0; j < 8; ++j) {
        float vs = F1sT[(size_t)h * 512 + t + j];
        float ve = F1eT[(size_t)h * 512 + t + j];
        p2 += tb2[t + j] * vs;
        shi[j] = (short)f2bf(vs);
        ushort_t hi = f2bf(ve);
        ehi[j] = (short)hi;
        elo[j] = (short)f2bf(ve - bf2f(hi));
    }
    *(short8*)(F1sT_bf + (size_t)h * 512 + t) = shi;
    size_t row = (size_t)(768 + h) * 1536;
    *(short8*)(B1cat + row + t) = ehi;
    *(short8*)(B1cat + row + 512 + t) = ehi;
    *(short8*)(B1cat + row + 1024 + t) = elo;
    for (int o = 32; o > 0; o >>= 1) p2 += __shfl_xor(p2, o);
    if (lane == 0) p2v[h] = p2;
}

// ---------------- K_g1: split-K G1 partials: partialG[kch] = A1cat @ B1cat^T chunk ----------------
// M=512, N=1024, K=1536 split into 8 chunks of 192 (3 kt of 64). grid 256 = kch(8) x [nt(8) x mt(4)].
__global__ __launch_bounds__(256) void k_g1(const ushort_t* __restrict__ A, const ushort_t* __restrict__ Bm,
                                            float* __restrict__ partialG) {
    __shared__ ushort_t As[128 * 72];
    __shared__ ushort_t Bs[128 * 72];
    int tid = threadIdx.x;
    int lane = tid & 63, wid = tid >> 6;
    int wr = wid >> 1, wc = wid & 1;
    int bid = blockIdx.x;
    int kch = bid & 7, tilei = bid >> 3;
    int nt = tilei & 7, mt = tilei >> 3;
    int m0 = mt * 128, n0 = nt * 128;
    f32x4 acc[4][4] = {};
    for (int kt = 0; kt < 3; ++kt) {
        int kb = kch * 192 + kt * 64;
        __syncthreads();
        {
            uint4 va[4], vb[4];
            for (int i = 0; i < 4; ++i) {
                int q = tid + i * 256;
                int row = q >> 3, kcc = (q & 7) << 3;
                va[i] = *(const uint4*)(A + (size_t)(m0 + row) * 1536 + kb + kcc);
                vb[i] = *(const uint4*)(Bm + (size_t)(n0 + row) * 1536 + kb + kcc);
            }
            for (int i = 0; i < 4; ++i) {
                int q = tid + i * 256;
                int row = q >> 3, kcc = (q & 7) << 3;
                *(uint4*)&As[row * 72 + kcc] = va[i];
                *(uint4*)&Bs[row * 72 + kcc] = vb[i];
            }
        }
        __syncthreads();
        for (int ks = 0; ks < 2; ++ks) {
            short8 a[4], b[4];
            int kk = ks * 32 + (lane >> 4) * 8;
            for (int mi = 0; mi < 4; ++mi)
                a[mi] = *(const short8*)&As[(wr * 64 + mi * 16 + (lane & 15)) * 72 + kk];
            for (int ni = 0; ni < 4; ++ni)
                b[ni] = *(const short8*)&Bs[(wc * 64 + ni * 16 + (lane & 15)) * 72 + kk];
            for (int mi = 0; mi < 4; ++mi)
                for (int ni = 0; ni < 4; ++ni)
                    acc[mi][ni] = __builtin_amdgcn_mfma_f32_16x16x32_bf16(a[mi], b[ni], acc[mi][ni], 0, 0, 0);
        }
    }
    float* pbase = partialG + (size_t)kch * 524288;
    int mb0 = m0 + wr * 64 + ((lane >> 4) << 2);
    int nb0 = n0 + wc * 64 + (lane & 15);
    for (int mi = 0; mi < 4; ++mi)
        for (int ni = 0; ni < 4; ++ni) {
            int mbase = mb0 + mi * 16;
            int n = nb0 + ni * 16;
            for (int r = 0; r < 4; ++r)
                pbase[(size_t)(mbase + r) * 1024 + n] = acc[mi][ni][r];
        }
}

// ---------------- K_reduceG1: sum 8 partials, route epilogue to s / hl / h2c ----------------
__global__ __launch_bounds__(256) void k_reduceG1(const float* __restrict__ partialG, const float* __restrict__ tb1,
                                                  float* __restrict__ s, ushort_t* __restrict__ hl,
                                                  float* __restrict__ h2c) {
    int id = blockIdx.x * 256 + threadIdx.x;   // grid 2048 -> 524288
    int m = id >> 10, n = id & 1023;
    float acc = 0.f;
#pragma unroll
    for (int kc = 0; kc < 8; ++kc)
        acc += partialG[(size_t)kc * 524288 + id];
    if (n < 512) s[(size_t)m * 512 + n] = acc;
    else if (n < 768) hl[(size_t)m * 256 + (n - 512)] = f2bf(leaky_(acc + tb1[n - 512]));
    else h2c[(size_t)m * 256 + (n - 768)] = acc;
}

// ---------------- K_p2: P2T = (tw2 @ F1s^T)^T store; M=N=256, K=512; grid 4 ----------------
__global__ __launch_bounds__(256) void k_p2(const ushort_t* __restrict__ A, const ushort_t* __restrict__ Bm,
                                            ushort_t* __restrict__ P2T) {
    __shared__ ushort_t As[128 * 72];
    __shared__ ushort_t Bs[128 * 72];
    int tid = threadIdx.x;
    int lane = tid & 63, wid = tid >> 6;
    int wr = wid >> 1, wc = wid & 1;
    int bid = blockIdx.x;
    int nt = bid & 1, mt = bid >> 1;
    int m0 = mt * 128, n0 = nt * 128;
    f32x4 acc[4][4] = {};
    for (int kt = 0; kt < 8; ++kt) {
        int kb = kt * 64;
        __syncthreads();
        {
            uint4 va[4], vb[4];
            for (int i = 0; i < 4; ++i) {
                int q = tid + i * 256;
                int row = q >> 3, kcc = (q & 7) << 3;
                va[i] = *(const uint4*)(A + (size_t)(m0 + row) * 512 + kb + kcc);
                vb[i] = *(const uint4*)(Bm + (size_t)(n0 + row) * 512 + kb + kcc);
            }
            for (int i = 0; i < 4; ++i) {
                int q = tid + i * 256;
                int row = q >> 3, kcc = (q & 7) << 3;
                *(uint4*)&As[row * 72 + kcc] = va[i];
                *(uint4*)&Bs[row * 72 + kcc] = vb[i];
            }
        }
        __syncthreads();
        for (int ks = 0; ks < 2; ++ks) {
            short8 a[4], b[4];
            int kk = ks * 32 + (lane >> 4) * 8;
            for (int mi = 0; mi < 4; ++mi)
                a[mi] = *(const short8*)&As[(wr * 64 + mi * 16 + (lane & 15)) * 72 + kk];
            for (int ni = 0; ni < 4; ++ni)
                b[ni] = *(const short8*)&Bs[(wc * 64 + ni * 16 + (lane & 15)) * 72 + kk];
            for (int mi = 0; mi < 4; ++mi)
                for (int ni = 0; ni < 4; ++ni)
                    acc[mi][ni] = __builtin_amdgcn_mfma_f32_16x16x32_bf16(a[mi], b[ni], acc[mi][ni], 0, 0, 0);
        }
    }
    int mb0 = m0 + wr * 64 + ((lane >> 4) << 2);
    int nb0 = n0 + wc * 64 + (lane & 15);
    for (int mi = 0; mi < 4; ++mi)
        for (int ni = 0; ni < 4; ++ni) {
            int mbase = mb0 + mi * 16;
            int n = nb0 + ni * 16;
            ushort4 o;
            o.x = f2bf(acc[mi][ni][0]);
            o.y = f2bf(acc[mi][ni][1]);
            o.z = f2bf(acc[mi][ni][2]);
            o.w = f2bf(acc[mi][ni][3]);
            *(ushort4*)(P2T + (size_t)n * 256 + mbase) = o;
        }
}

// ---------------- GEMM0: M2T = Wt @ fw1T^T (M=512, N=32768, K=512) ----------------
__global__ __launch_bounds__(512) void k_gemm0(const ushort_t* __restrict__ A, const ushort_t* __restrict__ Bm,
                                               ushort_t* __restrict__ M2T) {
    __shared__ ushort_t As[2][128 * 64];
    __shared__ ushort_t Bs[2][128 * 64];
    int tid = threadIdx.x;
    int lane = tid & 63, wid = tid >> 6;
    int wr = wid >> 2, wc = wid & 3;          // 2 x 4 waves; wave tile 64m x 32n
    int bid = blockIdx.x;
    int xx = bid & 7, y = bid >> 3;
    int mt = y & 3;
    int nt = ((y >> 2) << 3) | xx;
    int m0 = mt * 128, n0 = nt * 128;
    int lrow = lane >> 3;                     // 0..7
    int sg = (lane & 7) ^ lrow;               // swizzled source 16B-slot
    auto issue = [&](int kt, int buf) {
        int kb = kt * 64;
        for (int i = 0; i < 2; ++i) {
            int rbase = wid * 16 + i * 8;
            gload_lds16(A + (size_t)(m0 + rbase + lrow) * 512 + kb + sg * 8, &As[buf][wid * 1024 + i * 512]);
            gload_lds16(Bm + (size_t)(n0 + rbase + lrow) * 512 + kb + sg * 8, &Bs[buf][wid * 1024 + i * 512]);
        }
    };
    f32x4 acc[4][2] = {};
    issue(0, 0);
    __syncthreads();
    int cur = 0;
    for (int kt = 0; kt < 8; ++kt) {
        int nxt = cur ^ 1;
        if (kt + 1 < 8) issue(kt + 1, nxt);
        __builtin_amdgcn_s_setprio(1);
        for (int ks = 0; ks < 2; ++ks) {
            short8 a[4], b[2];
            int sl = ks * 4 + (lane >> 4);
            for (int mi = 0; mi < 4; ++mi) {
                int row = wr * 64 + mi * 16 + (lane & 15);
                a[mi] = *(const short8*)&As[cur][row * 64 + ((sl ^ (row & 7)) << 3)];
            }
            for (int ni = 0; ni < 2; ++ni) {
                int row = wc * 32 + ni * 16 + (lane & 15);
                b[ni] = *(const short8*)&Bs[cur][row * 64 + ((sl ^ (row & 7)) << 3)];
            }
            for (int mi = 0; mi < 4; ++mi)
                for (int ni = 0; ni < 2; ++ni)
                    acc[mi][ni] = __builtin_amdgcn_mfma_f32_16x16x32_bf16(a[mi], b[ni], acc[mi][ni], 0, 0, 0);
        }
        __builtin_amdgcn_s_setprio(0);
        __syncthreads();
        cur = nxt;
    }
    // epilogue: stage 128x128 bf16 C tile across As[0..1] (exactly 32KB), swizzled, then linear copy
    ushort_t* cstage = &As[0][0];
    for (int mi = 0; mi < 4; ++mi) {
        int ml = wr * 64 + mi * 16 + ((lane >> 4) << 2);
        for (int ni = 0; ni < 2; ++ni) {
            int nl = wc * 32 + ni * 16 + (lane & 15);
            for (int r = 0; r < 4; ++r) {
                int row = ml + r;
                cstage[row * 128 + (nl ^ ((row & 7) << 4))] = f2bf(acc[mi][ni][r]);
            }
        }
    }
    __syncthreads();
    short8* d8 = (short8*)(M2T + ((size_t)(n0 >> 7) << 16) + (size_t)m0 * 128);
    for (int i = 0; i < 4; ++i) {
        int p = tid + i * 512;                 // short8 index 0..2047
        int row = p >> 4;
        int col0 = (p & 15) * 8;
        d8[p] = *(const short8*)&cstage[row * 128 + (col0 ^ ((row & 7) << 4))];
    }
}

// ---------------- GEMM1 (fused): partial[kc] = cook(s) @ M2T^T chunk ----------------
__global__ __launch_bounds__(512) void k_gemm1(const float* __restrict__ s,
                                               const ushort_t* __restrict__ Atab, const ushort_t* __restrict__ Btab,
                                               const float* __restrict__ bpkey,
                                               const ushort_t* __restrict__ Bm,
                                               float* __restrict__ partial) {
    __shared__ ushort_t As[2][128 * 64];
    __shared__ ushort_t Bs[2][128 * 64];
    __shared__ float sv_s[1024];
    __shared__ ushort_t r_s[1024];
    __shared__ float bp_s[256];
    int tid = threadIdx.x;
    int lane = tid & 63, wid = tid >> 6;
    int wr = wid >> 2, wc = wid & 3;           // 2 x 4 waves; wave tile 64m x 32n
    int bid = blockIdx.x;
    int xcd = bid & 7, j = bid >> 3;           // j: 0..63
    int kcl = j & 7, mt = (j >> 3) & 3, nt = j >> 5;
    int kc = xcd * 8 + kcl;                    // 0..63
    int m0 = mt * 128, n0 = nt * 128;
    int k0 = kc * 1024;
    if (tid < 256) bp_s[tid] = bpkey[tid];
    __syncthreads();
    {   // stage s-slice (128 rows x 8 k) + region lookup: 512 thr x float2
        int row = tid >> 2, j2 = (tid & 3) * 2;
        float2 sv2 = *(const float2*)(s + (size_t)(m0 + row) * 512 + kc * 8 + j2);
        float svv[2] = {sv2.x, sv2.y};
        for (int q = 0; q < 2; ++q) {
            float sv = svv[q];
            int lo = 0, hi = 256;
            while (lo < hi) { int mid = (lo + hi) >> 1; if (bp_s[mid] <= sv) lo = mid + 1; else hi = mid; }
            sv_s[row * 8 + j2 + q] = sv;
            r_s[row * 8 + j2 + q] = (ushort_t)lo;
        }
    }
    __syncthreads();

    int lrow = lane >> 3;
    int sg = (lane & 7) ^ lrow;
    auto issueB = [&](int kt, int buf) {
        int kb = k0 + kt * 64;
        for (int i = 0; i < 2; ++i) {
            int rbase = wid * 16 + i * 8;
            gload_lds16(Bm + (size_t)(n0 + rbase + lrow) * 65536 + kb + sg * 8, &Bs[buf][wid * 1024 + i * 512]);
        }
    };
    short8 ta[2], tb[2];
    float svr[2];
    auto gather = [&](int kt) {
        int kl = kt >> 1;
        for (int i = 0; i < 2; ++i) {
            int q = tid + i * 512;
            int row = q >> 3, slot = q & 7;
            int e0 = ((kt & 1) << 6) + slot * 8;
            int r = r_s[row * 8 + kl];
            svr[i] = sv_s[row * 8 + kl];
            ta[i] = *(const short8*)(Atab + r * 128 + e0);
            tb[i] = *(const short8*)(Btab + r * 128 + e0);
        }
    };
    auto cookwrite = [&](int buf) {
        for (int i = 0; i < 2; ++i) {
            int q = tid + i * 512;
            int row = q >> 3, slot = q & 7;
            float sv = svr[i];
            short8 o;
            for (int jj = 0; jj < 8; ++jj) {
                float y = fmaf(sv, bf2f((ushort_t)ta[i][jj]), bf2f((ushort_t)tb[i][jj]));
                y = y - fminf(fmaxf(y, -LAMBDA_), LAMBDA_);
                o[jj] = (short)f2bf(y);
            }
            *(short8*)&As[buf][row * 64 + ((slot ^ (row & 7)) << 3)] = o;
        }
    };

    f32x4 acc[4][2] = {};
    issueB(0, 0);
    gather(0);
    cookwrite(0);
    __syncthreads();
    int cur = 0;
    for (int kt = 0; kt < 16; ++kt) {
        int nxt = cur ^ 1;
        if (kt + 1 < 16) { issueB(kt + 1, nxt); gather(kt + 1); }
        __builtin_amdgcn_s_setprio(1);
        for (int ks = 0; ks < 2; ++ks) {
            short8 a[4], b[2];
            int sl = ks * 4 + (lane >> 4);
            for (int mi = 0; mi < 4; ++mi) {
                int row = wr * 64 + mi * 16 + (lane & 15);
                a[mi] = *(const short8*)&As[cur][row * 64 + ((sl ^ (row & 7)) << 3)];
            }
            for (int ni = 0; ni < 2; ++ni) {
                int row = wc * 32 + ni * 16 + (lane & 15);
                b[ni] = *(const short8*)&Bs[cur][row * 64 + ((sl ^ (row & 7)) << 3)];
            }
            for (int mi = 0; mi < 4; ++mi)
                for (int ni = 0; ni < 2; ++ni)
                    acc[mi][ni] = __builtin_amdgcn_mfma_f32_16x16x32_bf16(a[mi], b[ni], acc[mi][ni], 0, 0, 0);
        }
        __builtin_amdgcn_s_setprio(0);
        if (kt + 1 < 16) cookwrite(nxt);
        __syncthreads();
        cur = nxt;
    }
    int mb0 = m0 + wr * 64 + ((lane >> 4) << 2);
    int nb0 = wc * 32 + (lane & 15);
    float* pbase = partial + (size_t)kc * 131072 + n0;
    for (int mi = 0; mi < 4; ++mi)
        for (int ni = 0; ni < 2; ++ni) {
            int mbase = mb0 + mi * 16;
            int n = nb0 + ni * 16;
            for (int r = 0; r < 4; ++r)
                pbase[(size_t)(mbase + r) * 256 + n] = acc[mi][ni][r];
        }
}

// ---------------- K10: final: h2b-row (hl@P2T) computed inline; a=leaky(sum+...); out=a@fw2+fb2 ----------------
__global__ __launch_bounds__(128) void k_final(const float* __restrict__ partial, const ushort_t* __restrict__ hl,
                                               const ushort_t* __restrict__ P2T, const float* __restrict__ p2v,
                                               const float* __restrict__ h2c, const float* __restrict__ fb1,
                                               const float* __restrict__ fw2, const float* __restrict__ fb2,
                                               float* __restrict__ out) {
    __shared__ float a_s[256];
    __shared__ float hl_s[256];
    int bn = blockIdx.x;
    int tid = threadIdx.x;
    {
        uint v = *(const uint*)(hl + (size_t)bn * 256 + tid * 2);
        hl_s[tid * 2] = bf2f((ushort_t)(v & 0xffff));
        hl_s[tid * 2 + 1] = bf2f((ushort_t)(v >> 16));
    }
    __syncthreads();
    for (int p = 0; p < 2; ++p) {
        int i = tid + p * 128;
        float acc = p2v[i] + h2c[(size_t)bn * 256 + i] + fb1[i];
#pragma unroll 8
        for (int kc = 0; kc < 64; ++kc)
            acc += partial[((size_t)kc * 512 + bn) * 256 + i];
        const ushort_t* prow = P2T + (size_t)i * 256;
#pragma unroll 4
        for (int jb = 0; jb < 32; ++jb) {
            short8 pv = *(const short8*)(prow + jb * 8);
            for (int j8 = 0; j8 < 8; ++j8)
                acc += hl_s[jb * 8 + j8] * bf2f((ushort_t)pv[j8]);
        }
        a_s[i] = leaky_(acc);
    }
    __syncthreads();
    if (tid < 96) {
        float acc = fb2[tid];
        for (int hh = 0; hh < 256; ++hh)
            acc += a_s[hh] * fw2[hh * 96 + tid];
        int b = bn >> 6, n = bn & 63;
        out[(size_t)(b * 96 + tid) * 64 + n] = acc;
    }
}

extern "C" void kernel_launch(void* const* d_in, const int* in_sizes, int n_in,
                              void* d_out, int out_size, void* d_ws, size_t ws_size,
                              hipStream_t stream) {
    const float* x   = (const float*)d_in[0];
    const float* emb = (const float*)d_in[1];
    const float* w1  = (const float*)d_in[2];
    const float* b1  = (const float*)d_in[3];
    const float* w2  = (const float*)d_in[4];
    const float* b2  = (const float*)d_in[5];
    const float* tw1 = (const float*)d_in[6];
    const float* tb1 = (const float*)d_in[7];
    const float* tw2 = (const float*)d_in[8];
    const float* tb2 = (const float*)d_in[9];
    const float* fw1 = (const float*)d_in[10];
    const float* fb1 = (const float*)d_in[11];
    const float* fw2 = (const float*)d_in[12];
    const float* fb2 = (const float*)d_in[13];
    float* out = (float*)d_out;

    char* W = (char*)d_ws;
    size_t off = 0;
    auto take = [&](size_t bytes) { size_t r = off; off += (bytes + 255) & ~(size_t)255; return r; };
    ushort_t* fw1T  = (ushort_t*)(W + take(33554432));        // [32768 j''=h*128+e][512 t] bf16
    ushort_t* M2T   = (ushort_t*)(W + take(33554432));        // [256 h][65536 k'] bf16
    float* partial  = (float*)(W + take(64 * 512 * 256 * 4)); // [64 kc][512 bn][256 h] f32
    float* partialG = (float*)(W + take(8 * 512 * 1024 * 4)); // [8 kch][512 bn][1024 n] f32
    ushort_t* A1cat = (ushort_t*)(W + take(512 * 1536 * 2));
    ushort_t* B1cat = (ushort_t*)(W + take(1024 * 1536 * 2));
    ushort_t* Wt    = (ushort_t*)(W + take(512 * 512 * 2));
    ushort_t* tw2bf = (ushort_t*)(W + take(256 * 512 * 2));
    float* F1T      = (float*)(W + take(2 * 256 * 512 * 4)); // [2][h][t]
    ushort_t* F1sbf = (ushort_t*)(W + take(256 * 512 * 2));
    float* sbuf     = (float*)(W + take(512 * 512 * 4));
    ushort_t* hlbuf = (ushort_t*)(W + take(512 * 256 * 2));
    float* h2c      = (float*)(W + take(512 * 256 * 4));
    ushort_t* P2T   = (ushort_t*)(W + take(256 * 256 * 2));
    float* p2v      = (float*)(W + take(256 * 4));
    ushort_t* Atab  = (ushort_t*)(W + take(257 * 128 * 2));
    ushort_t* Btab  = (ushort_t*)(W + take(257 * 128 * 2));
    float* bpkey    = (float*)(W + take(256 * 4));
    float* u_g      = (float*)(W + take(256 * 4));
    int* idxs_g     = (int*)(W + take(256 * 4));
    (void)ws_size; (void)in_sizes; (void)n_in; (void)out_size;

    // merged setup | pack_tw1 | transpose_x
    k_pre<<<3360, 256, 0, stream>>>(x, tw1, tw2, A1cat, B1cat, Wt, tw2bf);
    k_prep1<<<1, 256, 0, stream>>>(emb, w1, b1, u_g, idxs_g, bpkey);
    k_prep2<<<128, 256, 0, stream>>>(u_g, b1, w2, b2, idxs_g, Atab, Btab);
    k_transpose_fw1<<<4096, 256, 0, stream>>>(fw1, fw1T);
    k_reduce_F2<<<256, 256, 0, stream>>>(fw1T, emb, F1T);
    k_pack_F<<<256, 64, 0, stream>>>(F1T, F1T + 131072, tb2, B1cat, F1sbf, p2v);
    // G1 split-K: partialG[kch] = xTcat @ B1cat^T chunk  (M=512, N=1024, K=1536/8)
    k_g1<<<256, 256, 0, stream>>>(A1cat, B1cat, partialG);
    k_reduceG1<<<2048, 256, 0, stream>>>(partialG, tb1, sbuf, hlbuf, h2c);
    // GEMM0: M2T = Wt @ fw1T^T  (M=512 k, N=32768 j'', K=512 t)
    k_gemm0<<<1024, 512, 0, stream>>>(Wt, fw1T, M2T);
    // P2' = tw2 @ F1s  (M=256, N=256, K=512) -> P2T
    k_p2<<<4, 256, 0, stream>>>(tw2bf, F1sbf, P2T);
    // GEMM1 (fused softshrink-A): partial[kc] = cook(s) @ M2T^T  (split-K 64)
    k_gemm1<<<512, 512, 0, stream>>>(sbuf, Atab, Btab, bpkey, M2T, partial);
    // final (h2b GEMM folded in)
    k_final<<<512, 128, 0, stream>>>(partial, hlbuf, P2T, p2v, h2c, fb1, fw2, fb2, out);
}